// Round 1
// baseline (910.102 us; speedup 1.0000x reference)
//
#include <hip/hip_runtime.h>
#include <hip/hip_bf16.h>
#include <hip/hip_fp16.h>

// Inputs/outputs are FP32 (verified R3/R6).
// R10 lesson: KV-in-regs OR weights-in-regs — never both (VGPR cap 256 -> spill).
// R11 (this round): decoder restructured to 4 barriers/step via redundant
// broadcast-stages on all waves + per-wave LDS transpose buffers (wsync only);
// multi-accumulator dots (4x/8x shorter FMA dep chains); PE table in LDS.

constexpr int kB  = 128;
constexpr int kS  = 512;
constexpr int kT  = 64;
constexpr int kD  = 48;
constexpr int kFF = 128;
constexpr int kNH = 4;
constexpr int kHD = 12;

__device__ __forceinline__ void wsync(){
  __builtin_amdgcn_wave_barrier();
  asm volatile("" ::: "memory");
}

__device__ __forceinline__ float wsum(float v){
  #pragma unroll
  for(int o=32;o>=1;o>>=1) v += __shfl_xor(v,o,64);
  return v;
}

// pe[p, 2i] = sin(p * exp(-2i*ln(10000)/48)), pe[p, 2i+1] = cos(...)
// precise version (decoder table init, runs once)
__device__ __forceinline__ float pe_val(int p, int j){
  int i = j >> 1;
  float f = expf(-0.19188209108283716f * (float)(2*i));
  float a = (float)p * f;
  return (j & 1) ? cosf(a) : sinf(a);
}
// fast version (encoder embed, 3.1M calls; err ~3e-5 << fp16 weight rounding)
__device__ __forceinline__ float pe_fast(int p, int j){
  int i = j >> 1;
  float f = __expf(-0.19188209108283716f * (float)(2*i));
  float a = (float)p * f;
  return (j & 1) ? __cosf(a) : __sinf(a);
}

union F4H8 { float4 f4; __half2 h2[4]; };

// dot of 48-float x (12 float4) with 48 fp16 LDS weights — 4 accumulators
// (hipcc won't reassociate fp32; single-acc chain was 48 dependent FMAs)
__device__ __forceinline__ float dot48h(const float4* x, const __half* w){
  const float4* w4=(const float4*)w;
  float a0=0.f,a1=0.f,a2=0.f,a3=0.f;
  #pragma unroll
  for(int c=0;c<6;c++){
    F4H8 u; u.f4=w4[c];
    float2 f0=__half22float2(u.h2[0]), f1=__half22float2(u.h2[1]);
    float2 f2=__half22float2(u.h2[2]), f3=__half22float2(u.h2[3]);
    float4 x0=x[2*c], x1=x[2*c+1];
    a0 += x0.x*f0.x; a1 += x0.y*f0.y; a2 += x0.z*f1.x; a3 += x0.w*f1.y;
    a0 += x1.x*f2.x; a1 += x1.y*f2.y; a2 += x1.z*f3.x; a3 += x1.w*f3.y;
  }
  return (a0+a1)+(a2+a3);
}
// 128-dot with 8 accumulators (chain 512 -> ~64 dependent cycles)
__device__ __forceinline__ float dot128h(const float4* x, const __half* w){
  const float4* w4=(const float4*)w;
  float a0=0.f,a1=0.f,a2=0.f,a3=0.f,a4=0.f,a5=0.f,a6=0.f,a7=0.f;
  #pragma unroll
  for(int c=0;c<16;c++){
    F4H8 u; u.f4=w4[c];
    float2 f0=__half22float2(u.h2[0]), f1=__half22float2(u.h2[1]);
    float2 f2=__half22float2(u.h2[2]), f3=__half22float2(u.h2[3]);
    float4 x0=x[2*c], x1=x[2*c+1];
    a0 += x0.x*f0.x; a1 += x0.y*f0.y; a2 += x0.z*f1.x; a3 += x0.w*f1.y;
    a4 += x1.x*f2.x; a5 += x1.y*f2.y; a6 += x1.z*f3.x; a7 += x1.w*f3.y;
  }
  return ((a0+a1)+(a2+a3))+((a4+a5)+(a6+a7));
}
__device__ __forceinline__ float dot12f(const float4* x, const float4* k){
  float a=0.f;
  #pragma unroll
  for(int u=0;u<3;u++){ float4 xx=x[u], kk=k[u];
    a+=xx.x*kk.x+xx.y*kk.y+xx.z*kk.z+xx.w*kk.w; }
  return a;
}

// ---------------- K1: embed + PE -> X0 (fp32) ----------------
__global__ void k_embed(const float* __restrict__ src, const float* __restrict__ in_w,
                        const float* __restrict__ in_b, float* __restrict__ X0){
  int idx = blockIdx.x*256 + threadIdx.x;
  if (idx >= kB*kS*kD) return;
  int j = idx % kD; int bs = idx / kD; int s = bs % kS;
  float v = (src[bs] * in_w[j] + in_b[j]) * 6.928203230275509f;
  X0[idx] = v + pe_fast(s, j);
}

// ---------------- K2: encoder QKV projection, fp16 W^T in LDS (R10) ----------------
__global__ void __launch_bounds__(256) k_qkv(const float* __restrict__ X,
    const float* __restrict__ wq, const float* __restrict__ bq,
    const float* __restrict__ wk, const float* __restrict__ bk,
    const float* __restrict__ wv, const float* __restrict__ bv,
    __half* __restrict__ Q, __half* __restrict__ K, __half* __restrict__ V){
  __shared__ __align__(16) __half W[3*2688];     // col stride 56 halves
  __shared__ __align__(16) float bias[3*kD];
  __shared__ __align__(16) float xt[32*kD];
  int tid = threadIdx.x;
  for (int i=tid;i<3*2304;i+=256){ int m=i/2304, e=i%2304, k=e/48, j=e%48;
    const float* w = (m==0)?wq:((m==1)?wk:wv);
    W[m*2688 + j*56 + k] = __float2half(w[e]); }
  for (int i=tid;i<3*kD;i+=256){ int m=i/kD,e=i%kD;
    const float* w=(m==0)?bq:((m==1)?bk:bv); bias[i]=w[e]; }
  long row0 = (long)blockIdx.x*32;
  for (int i=tid;i<32*kD;i+=256) xt[i] = X[row0*kD + i];
  __syncthreads();
  int r = tid>>3, c0 = tid&7;
  float4 xr[12];
  const float4* xp=(const float4*)(xt + r*kD);
  #pragma unroll
  for(int u=0;u<12;u++) xr[u]=xp[u];
  for (int c=c0; c<3*kD; c+=8){
    int m=c/kD, j=c%kD;
    float acc = bias[m*kD+j] + dot48h(xr, W + m*2688 + j*56);
    __half* o = (m==0)?Q:((m==1)?K:V);
    o[(row0+r)*kD+j]=__float2half(acc);
  }
}

// ---------------- K3: encoder attention — fp32 K/V staged in LDS (R10) ----------------
__global__ void __launch_bounds__(256) k_attn(const __half* Q, const __half* __restrict__ K,
                       const __half* __restrict__ V, __half* O){
  int b = blockIdx.x / kNH, h = blockIdx.x % kNH;
  __shared__ __align__(16) float Ks[kS*kHD];   // 24 KB, fp32 (no per-iter cvt)
  __shared__ __align__(16) float Vs[kS*kHD];
  int tid = threadIdx.x;
  long base = ((long)b*kS)*kD + h*kHD;
  for (int i=tid;i<kS*kHD;i+=256){ int r=i/kHD, d=i%kHD;
    Ks[i]=__half2float(K[base+(long)r*kD+d]);
    Vs[i]=__half2float(V[base+(long)r*kD+d]); }
  const float rs = 0.28867513459481287f;
  int q0 = tid, q1 = tid+256;
  float qa[kHD], qb[kHD];
  #pragma unroll
  for(int j=0;j<kHD;j++){
    qa[j]=__half2float(Q[base+(long)q0*kD+j])*rs;
    qb[j]=__half2float(Q[base+(long)q1*kD+j])*rs;
  }
  __syncthreads();
  float acc0[kHD], acc1[kHD];
  #pragma unroll
  for(int j=0;j<kHD;j++){ acc0[j]=0.f; acc1[j]=0.f; }
  float l0=0.f, l1=0.f;
  for(int k=0;k<kS;k++){
    const float4* kp=(const float4*)(Ks+k*kHD);  // broadcast reads
    const float4* vp=(const float4*)(Vs+k*kHD);
    float4 ka=kp[0], kb4=kp[1], kc4=kp[2];
    float kr[kHD]={ka.x,ka.y,ka.z,ka.w,kb4.x,kb4.y,kb4.z,kb4.w,kc4.x,kc4.y,kc4.z,kc4.w};
    float s0=0.f,s1=0.f;
    #pragma unroll
    for(int j=0;j<kHD;j++){ s0+=qa[j]*kr[j]; s1+=qb[j]*kr[j]; }
    float p0=__expf(s0), p1=__expf(s1);   // |s|<~42 << 88: exp-safe
    l0+=p0; l1+=p1;
    float4 va=vp[0], vb4=vp[1], vc4=vp[2];
    float vr[kHD]={va.x,va.y,va.z,va.w,vb4.x,vb4.y,vb4.z,vb4.w,vc4.x,vc4.y,vc4.z,vc4.w};
    #pragma unroll
    for(int j=0;j<kHD;j++){ acc0[j]+=p0*vr[j]; acc1[j]+=p1*vr[j]; }
  }
  float i0=1.f/l0, i1=1.f/l1;
  #pragma unroll
  for(int j=0;j<kHD;j++){
    O[base+(long)q0*kD+j]=__float2half(acc0[j]*i0);
    O[base+(long)q1*kD+j]=__float2half(acc1[j]*i1);
  }
}

// ---------------- K4: o-proj + residual + LN, fp16 W^T (R10) ----------------
__global__ void __launch_bounds__(256) k_oproj_ln(const float* __restrict__ Xres, const __half* __restrict__ O,
      const float* __restrict__ wo, const float* __restrict__ bo,
      const float* __restrict__ g, const float* __restrict__ bb,
      __half* __restrict__ Xout){
  __shared__ __align__(16) __half W[kD*56];
  __shared__ float bsh[kD], gs[kD], bs2[kD];
  __shared__ __align__(16) float res[32*kD];
  __shared__ __align__(16) float ot[32*kD];
  __shared__ float mrow[32], rstd[32];
  int tid=threadIdx.x;
  for(int i=tid;i<kD*kD;i+=256){ int k=i/48, j=i%48; W[j*56+k]=__float2half(wo[i]); }
  if(tid<kD){ bsh[tid]=bo[tid]; gs[tid]=g[tid]; bs2[tid]=bb[tid]; }
  long row0=(long)blockIdx.x*32;
  for(int i=tid;i<32*kD;i+=256) ot[i]=__half2float(O[row0*kD+i]);
  __syncthreads();
  int r=tid>>3, c0=tid&7;
  float4 orow[12];
  const float4* op=(const float4*)(ot + r*kD);
  #pragma unroll
  for(int u=0;u<12;u++) orow[u]=op[u];
  for(int j=c0;j<kD;j+=8){
    float acc=bsh[j]+dot48h(orow, W+j*56);
    res[r*kD+j]=Xres[row0*kD + r*kD + j]+acc;
  }
  __syncthreads();
  if(tid<32){
    float s=0.f, s2=0.f;
    for(int j=0;j<kD;j++){ float v=res[tid*kD+j]; s+=v; s2+=v*v; }
    float m=s*(1.f/kD);
    mrow[tid]=m; rstd[tid]=rsqrtf(s2*(1.f/kD)-m*m+1e-5f);
  }
  __syncthreads();
  for(int i=tid;i<32*kD;i+=256){int r2=i/kD,j=i%kD;
    Xout[row0*kD+i]=__float2half((res[i]-mrow[r2])*rstd[r2]*gs[j]+bs2[j]); }
}

// ---------------- K5: FFN + residual + LN, fp16 W^T (R10) ----------------
__global__ void __launch_bounds__(256) k_ffn_ln(const __half* __restrict__ Xin,
   const float* __restrict__ w1, const float* __restrict__ b1,
   const float* __restrict__ w2, const float* __restrict__ b2,
   const float* __restrict__ g, const float* __restrict__ bb,
   float* __restrict__ Xout){
  __shared__ __align__(16) __half W1[kFF*56];
  __shared__ __align__(16) __half W2[kD*136];
  __shared__ float b1s[kFF], b2s[kD], gs[kD], bs2[kD];
  __shared__ __align__(16) float xt[16*kD];
  __shared__ __align__(16) float h1v[16*kFF];
  __shared__ __align__(16) float res[16*kD];
  __shared__ float mrow[16], rstd[16];
  int tid=threadIdx.x;
  for(int i=tid;i<kD*kFF;i+=256){ int k=i/128, c=i%128; W1[c*56+k]=__float2half(w1[i]); }
  for(int i=tid;i<kFF*kD;i+=256){ int u=i/48, j=i%48; W2[j*136+u]=__float2half(w2[i]); }
  if(tid<kFF) b1s[tid]=b1[tid];
  if(tid<kD){ b2s[tid]=b2[tid]; gs[tid]=g[tid]; bs2[tid]=bb[tid]; }
  long row0=(long)blockIdx.x*16;
  for(int i=tid;i<16*kD;i+=256) xt[i]=__half2float(Xin[row0*kD+i]);
  __syncthreads();
  int r=tid>>4, c0=tid&15;
  {
    float4 xr[12];
    const float4* xp=(const float4*)(xt + r*kD);
    #pragma unroll
    for(int u=0;u<12;u++) xr[u]=xp[u];
    for(int c=c0;c<kFF;c+=16){
      float acc=b1s[c]+dot48h(xr, W1+c*56);
      h1v[r*kFF+c]=fmaxf(acc,0.f);
    }
  }
  __syncthreads();
  {
    float4 hr[32];
    const float4* hp=(const float4*)(h1v + r*kFF);
    #pragma unroll
    for(int u=0;u<32;u++) hr[u]=hp[u];
    for(int j=c0;j<kD;j+=16){
      float acc=b2s[j]+dot128h(hr, W2+j*136);
      res[r*kD+j]=xt[r*kD+j]+acc;
    }
  }
  __syncthreads();
  if(tid<16){
    float s=0.f, s2=0.f;
    for(int j=0;j<kD;j++){ float v=res[tid*kD+j]; s+=v; s2+=v*v; }
    float m=s*(1.f/kD);
    mrow[tid]=m; rstd[tid]=rsqrtf(s2*(1.f/kD)-m*m+1e-5f);
  }
  __syncthreads();
  for(int i=tid;i<16*kD;i+=256){int r2=i/kD,j=i%kD;
    Xout[row0*kD+i]=(res[i]-mrow[r2])*rstd[r2]*gs[j]+bs2[j]; }
}

// ---------------- K6: cross K/V projection, transposed fp16 out, fp16 W^T (R10) ----------------
__global__ void __launch_bounds__(256) k_ckv(const float* __restrict__ M,
    const float* __restrict__ wk, const float* __restrict__ bk,
    const float* __restrict__ wv, const float* __restrict__ bv,
    __half* __restrict__ Kc, __half* __restrict__ Vc){
  __shared__ __align__(16) __half W[2*2688];
  __shared__ float bias[2*kD];
  __shared__ __align__(16) float xt[32*kD];
  int tid=threadIdx.x;
  for(int i=tid;i<2*2304;i+=256){ int m=i/2304, e=i%2304, k=e/48, j=e%48;
    W[m*2688 + j*56 + k] = __float2half((m?wv:wk)[e]); }
  for(int i=tid;i<2*kD;i+=256){ int m=i/kD,e=i%kD; bias[i]=(m?bv:bk)[e]; }
  long row0=(long)blockIdx.x*32;
  for(int i=tid;i<32*kD;i+=256) xt[i]=M[row0*kD+i];
  __syncthreads();
  int r=tid>>3, c0=tid&7;
  float4 xr[12];
  const float4* xp=(const float4*)(xt + r*kD);
  #pragma unroll
  for(int u=0;u<12;u++) xr[u]=xp[u];
  long gr=row0+r; long bb2=gr>>9; long s=gr&511;
  for(int c=c0;c<2*kD;c+=8){
    int m=c/kD, j=c%kD;
    float acc=bias[m*kD+j]+dot48h(xr, W+m*2688+j*56);
    (m?Vc:Kc)[(bb2*kD+j)*kS+s]=__float2half(acc);
  }
}

// ---------------- K0: decoder weights -> padded FP16, column-major ----------------
// Wh halves: 6 mats 48 cols stride 56: swq@0 swk@2688 swv@5376 swo@8064 cwq@10752
// cwo@13440; w1 128 cols stride 56 @16128; w2 48 cols stride 136 @23296. Tot 29824.
__global__ void k_prep(const float* __restrict__ swq,const float* __restrict__ swk,
                       const float* __restrict__ swv,const float* __restrict__ swo,
                       const float* __restrict__ cwq,const float* __restrict__ cwo,
                       const float* __restrict__ w1,const float* __restrict__ w2,
                       __half* __restrict__ Wh){
  int idx=blockIdx.x*256+threadIdx.x;
  if(idx>=26112) return;
  if(idx<13824){
    int m=idx/2304, e=idx%2304, j=e/48, k=e%48;
    const float* w = (m==0)?swq:((m==1)?swk:((m==2)?swv:((m==3)?swo:((m==4)?cwq:cwo))));
    Wh[m*2688 + j*56 + k] = __float2half(w[k*48+j]);
  } else if(idx<19968){
    int e=idx-13824, c=e/48, k=e%48;
    Wh[16128 + c*56 + k] = __float2half(w1[k*128+c]);
  } else {
    int e=idx-19968, j=e/128, u=e%128;
    Wh[23296 + j*136 + u] = __float2half(w2[u*48+j]);
  }
}

// ---------------- K7: decoder — R11: 4 barriers/step, redundant broadcast-stages ----------------
// Cross-wave merges (true barriers): qkv->attn, attn->soS, cross-attn->covS, ffn1->f1S.
// Everything else (o-proj/LN/cross-q/FFN2/LN3/next-x) computed redundantly on ALL
// waves; vector forms pass through per-wave private LDS buffers with wsync only.
struct DecP {
  const float *dec_start, *sbq, *sbk, *sbv, *sbo, *ln1g, *ln1b,
              *cbq, *cbo, *ln2g, *ln2b, *fb1, *fb2, *ln3g, *ln3b, *ow, *ob;
};

__global__ void __launch_bounds__(256,1) k_dec(const __half* __restrict__ KT,
    const __half* __restrict__ VT, const __half* __restrict__ Wg, DecP P,
    float* __restrict__ out){
  __shared__ __align__(16) __half Wl[29824];       // fp16 weights, 58.25 KB
  __shared__ __align__(16) float Kh[kNH*kT*kHD];   // per-head self-K cache, 12 KB
  __shared__ __align__(16) float Vh[kNH*kT*kHD];
  __shared__ __align__(16) float qS[kNH*16];
  __shared__ __align__(16) float soS[kD], covS[kD];
  __shared__ __align__(16) float f1S[kFF];
  // per-wave private transpose buffers (48 floats = 192B rows, 16B aligned)
  __shared__ __align__(16) float xvW[4][kD], h1W[4][kD], cqW[4][kD], h2W[4][kD];
  __shared__ __align__(16) float peT[kT*kD];       // PE table, 12.3 KB (off critical path)
  int tid=threadIdx.x, b=blockIdx.x, wave=tid>>6, lane=tid&63;
  const float rs=0.28867513459481287f;

  for(int i=tid;i<29824/8;i+=256) ((float4*)Wl)[i]=((const float4*)Wg)[i];
  for(int i=tid;i<kT*kD;i+=256){ int tt=i/kD, j=i%kD; peT[i]=pe_val(tt,j); }

  // per-lane constants, replicated on ALL waves (redundant stages need them)
  float cur=0, c_bo=0,c_cbq=0,c_cbo=0,c_fb2=0;
  float g1=0,bb1=0,g2=0,bb2=0,g3=0,bb3=0,c_ow=0;
  if(lane<kD){
    cur=P.dec_start[lane];
    c_bo=P.sbo[lane]; c_cbq=P.cbq[lane]; c_cbo=P.cbo[lane]; c_fb2=P.fb2[lane];
    g1=P.ln1g[lane]; bb1=P.ln1b[lane];
    g2=P.ln2g[lane]; bb2=P.ln2b[lane];
    g3=P.ln3g[lane]; bb3=P.ln3b[lane];
    c_ow=P.ow[lane];
  }
  float c_qkvb=0;
  if(tid<144){ int m=tid/48, j=tid%48;
    c_qkvb = ((m==0)?P.sbq:((m==1)?P.sbk:P.sbv))[j]; }
  float c_fb1 = (tid<kFF) ? P.fb1[tid] : 0.f;
  float c_ob=P.ob[0];

  // cross-attn K/V resident in registers: head = wave, 4 key-pairs per lane
  __half2 Kr[4][kHD], Vr[4][kHD];
  {
    const __half2* KTb=(const __half2*)KT + (long)b*kD*(kS/2);
    const __half2* VTb=(const __half2*)VT + (long)b*kD*(kS/2);
    #pragma unroll
    for(int i=0;i<4;i++){
      int pp=lane+64*i;
      #pragma unroll
      for(int u=0;u<kHD;u++){
        Kr[i][u]=KTb[(wave*kHD+u)*(kS/2)+pp];
        Vr[i][u]=VTb[(wave*kHD+u)*(kS/2)+pp];
      }
    }
  }
  __syncthreads();

  float h1=0, h2=0, xv=0;
  for(int t=0;t<kT;t++){
    // (A) x per-lane on ALL waves; transpose into own wave's buffer (no barrier)
    if(lane<kD){ xv=cur+peT[t*kD+lane]; xvW[wave][lane]=xv; }
    wsync();
    // (B) qkv: 144 columns, one dot per thread, reading own wave's x copy
    if(tid<144){
      int m=tid/48, j=tid%48;
      float a=c_qkvb+dot48h((const float4*)xvW[wave], Wl + m*2688 + j*56);
      int hh=j/kHD, dd=j%kHD;
      if(m==0) qS[hh*16+dd]=a;
      else if(m==1) Kh[(hh*kT+t)*kHD+dd]=a;
      else          Vh[(hh*kT+t)*kHD+dd]=a;
    }
    __syncthreads();                                   // bar A (qkv -> attn)
    // (C) self-attn, head = wave, lane = key; probs in regs
    {
      float p=0.f, pv[kHD];
      #pragma unroll
      for(int u=0;u<kHD;u++) pv[u]=0.f;
      if(lane<=t){
        float s=dot12f((const float4*)(qS+wave*16),
                       (const float4*)(Kh+(wave*kT+lane)*kHD))*rs;
        p=__expf(s);
        const float4* vp=(const float4*)(Vh+(wave*kT+lane)*kHD);
        float4 v0=vp[0], v1=vp[1], v2=vp[2];
        float vr[kHD]={v0.x,v0.y,v0.z,v0.w,v1.x,v1.y,v1.z,v1.w,v2.x,v2.y,v2.z,v2.w};
        #pragma unroll
        for(int u=0;u<kHD;u++) pv[u]=p*vr[u];
      }
      float l=wsum(p);
      #pragma unroll
      for(int u=0;u<kHD;u++) pv[u]=wsum(pv[u]);
      if(lane==0){
        float inv=1.f/l;
        #pragma unroll
        for(int u=0;u<kHD;u++) soS[wave*kHD+u]=pv[u]*inv;
      }
    }
    __syncthreads();                                   // bar B (attn -> soS)
    // (D) REDUNDANT on all waves: self o-proj + residual + LN1 + cross-q
    {
      float rr=0.f;
      if(lane<kD)
        rr=xv+c_bo+dot48h((const float4*)soS, Wl+8064+lane*56);
      float s1=wsum(rr), s2=wsum(rr*rr);
      float mean=s1*(1.f/48.f);
      float rstd=rsqrtf(s2*(1.f/48.f)-mean*mean+1e-5f);
      h1=0.f;
      if(lane<kD){ h1=(rr-mean)*rstd*g1+bb1; h1W[wave][lane]=h1; }
      wsync();
      if(lane<kD)
        cqW[wave][lane]=c_cbq+dot48h((const float4*)h1W[wave], Wl+10752+lane*56);
      wsync();
    }
    // (E) cross-attn from registers, head = wave; q from own wave's copy
    {
      const float4* q4=(const float4*)(cqW[wave]);
      float4 qq0=q4[wave*3], qq1=q4[wave*3+1], qq2=q4[wave*3+2];
      float qh[kHD]={qq0.x,qq0.y,qq0.z,qq0.w,qq1.x,qq1.y,qq1.z,qq1.w,qq2.x,qq2.y,qq2.z,qq2.w};
      #pragma unroll
      for(int u=0;u<kHD;u++) qh[u]*=rs;
      float p[8], l=0.f;
      #pragma unroll
      for(int i=0;i<4;i++){
        float ax=0.f, ay=0.f;
        #pragma unroll
        for(int u=0;u<kHD;u++){ float2 kv=__half22float2(Kr[i][u]);
          ax+=qh[u]*kv.x; ay+=qh[u]*kv.y; }
        p[2*i]=__expf(ax); p[2*i+1]=__expf(ay);
        l+=p[2*i]+p[2*i+1];
      }
      l=wsum(l);
      float inv=1.f/l;
      float acc[kHD];
      #pragma unroll
      for(int u=0;u<kHD;u++) acc[u]=0.f;
      #pragma unroll
      for(int i=0;i<4;i++){
        #pragma unroll
        for(int u=0;u<kHD;u++){ float2 vv=__half22float2(Vr[i][u]);
          acc[u]+=p[2*i]*vv.x+p[2*i+1]*vv.y; }
      }
      #pragma unroll
      for(int u=0;u<kHD;u++) acc[u]=wsum(acc[u]);
      if(lane==0){
        #pragma unroll
        for(int u=0;u<kHD;u++) covS[wave*kHD+u]=acc[u]*inv;
      }
    }
    __syncthreads();                                   // bar C (cross-attn -> covS)
    // (F) REDUNDANT on all waves: cross o-proj + residual + LN2
    {
      float rr=0.f;
      if(lane<kD)
        rr=h1+c_cbo+dot48h((const float4*)covS, Wl+13440+lane*56);
      float s1=wsum(rr), s2=wsum(rr*rr);
      float mean=s1*(1.f/48.f);
      float rstd=rsqrtf(s2*(1.f/48.f)-mean*mean+1e-5f);
      h2=0.f;
      if(lane<kD){ h2=(rr-mean)*rstd*g2+bb2; h2W[wave][lane]=h2; }
      wsync();
    }
    // (G) FFN1 on tids 0..127 (waves 0,1), reading own wave's h2 copy
    if(tid<kFF){
      float a=c_fb1+dot48h((const float4*)h2W[wave], Wl+16128+tid*56);
      f1S[tid]=fmaxf(a,0.f);
    }
    __syncthreads();                                   // bar D (ffn1 -> f1S)
    // (H) REDUNDANT on all waves: FFN2 + residual + LN3 + next-x; wave0 emits y
    {
      float rr=0.f;
      if(lane<kD)
        rr=h2+c_fb2+dot128h((const float4*)f1S, Wl+23296+lane*136);
      float s1=wsum(rr), s2=wsum(rr*rr);
      float mean=s1*(1.f/48.f);
      float rstd=rsqrtf(s2*(1.f/48.f)-mean*mean+1e-5f);
      float cv=0.f;
      if(lane<kD) cv=(rr-mean)*rstd*g3+bb3;
      cur=cv;
      if(wave==0){
        float y=wsum(cv*c_ow);
        if(lane==0) out[b*kT+t]=y+c_ob;
      }
    }
  }
}

extern "C" void kernel_launch(void* const* d_in, const int* in_sizes, int n_in,
                              void* d_out, int out_size, void* d_ws, size_t ws_size,
                              hipStream_t stream){
  // ws: Wh fp16 (reserve 65536 B), A fp32 NB, H1/H2/H3 fp16 NB each (~31.5 MiB).
  float* ws = (float*)d_ws;
  __half* Wh = (__half*)ws;
  const size_t NB = (size_t)kB*kS*kD;     // 3,145,728
  float*  A  = ws + 16384;
  __half* H1 = (__half*)(A + NB);
  __half* H2 = H1 + NB;
  __half* H3 = H2 + NB;

  k_embed<<<(kB*kS*kD+255)/256,256,0,stream>>>((const float*)d_in[0],(const float*)d_in[1],(const float*)d_in[2],A);
  k_qkv  <<<(kB*kS)/32,256,0,stream>>>(A,(const float*)d_in[4],(const float*)d_in[5],(const float*)d_in[6],
                                       (const float*)d_in[7],(const float*)d_in[8],(const float*)d_in[9],H1,H2,H3);
  k_attn <<<kB*kNH,256,0,stream>>>(H1,H2,H3,H1);
  k_oproj_ln<<<(kB*kS)/32,256,0,stream>>>(A,H1,(const float*)d_in[10],(const float*)d_in[11],
                                          (const float*)d_in[12],(const float*)d_in[13],H2);
  k_ffn_ln  <<<(kB*kS)/16,256,0,stream>>>(H2,(const float*)d_in[14],(const float*)d_in[15],(const float*)d_in[16],
                                          (const float*)d_in[17],(const float*)d_in[18],(const float*)d_in[19],A);
  k_ckv     <<<(kB*kS)/32,256,0,stream>>>(A,(const float*)d_in[32],(const float*)d_in[33],
                                          (const float*)d_in[34],(const float*)d_in[35],H1,H3);
  k_prep    <<<(26112+255)/256,256,0,stream>>>((const float*)d_in[20],(const float*)d_in[22],(const float*)d_in[24],
                                               (const float*)d_in[26],(const float*)d_in[30],(const float*)d_in[36],
                                               (const float*)d_in[40],(const float*)d_in[42],Wh);
  DecP P;
  P.dec_start=(const float*)d_in[3];
  P.sbq=(const float*)d_in[21]; P.sbk=(const float*)d_in[23]; P.sbv=(const float*)d_in[25]; P.sbo=(const float*)d_in[27];
  P.ln1g=(const float*)d_in[28]; P.ln1b=(const float*)d_in[29];
  P.cbq=(const float*)d_in[31]; P.cbo=(const float*)d_in[37];
  P.ln2g=(const float*)d_in[38]; P.ln2b=(const float*)d_in[39];
  P.fb1=(const float*)d_in[41]; P.fb2=(const float*)d_in[43];
  P.ln3g=(const float*)d_in[44]; P.ln3b=(const float*)d_in[45];
  P.ow=(const float*)d_in[46]; P.ob=(const float*)d_in[47];
  k_dec<<<kB,256,0,stream>>>(H1,H3,Wh,P,(float*)d_out);
}

// Round 2
// 688.489 us; speedup vs baseline: 1.3219x; 1.3219x over previous
//
#include <hip/hip_runtime.h>
#include <hip/hip_bf16.h>
#include <hip/hip_fp16.h>

// Inputs/outputs are FP32 (verified R3/R6).
// R10 lesson: KV-in-regs OR weights-in-regs — never both (VGPR cap 256 -> spill).
// R11 lesson: redundant all-wave broadcast stages LOSE (4x LDS traffic > 3 barriers);
//             decoder is stall-bound on the serial chain -> shrink instruction count.
// R12: v_dot2_f32_f16 everywhere (24 dot2 per 48-dot vs 48 cvt + 48 fma);
//      fp16 activations through LDS, fp32 residual/LN in regs; PE table kept.

constexpr int kB  = 128;
constexpr int kS  = 512;
constexpr int kT  = 64;
constexpr int kD  = 48;
constexpr int kFF = 128;
constexpr int kNH = 4;
constexpr int kHD = 12;

__device__ __forceinline__ void wsync(){
  __builtin_amdgcn_wave_barrier();
  asm volatile("" ::: "memory");
}

__device__ __forceinline__ float wsum(float v){
  #pragma unroll
  for(int o=32;o>=1;o>>=1) v += __shfl_xor(v,o,64);
  return v;
}
__device__ __forceinline__ float wmax(float v){
  #pragma unroll
  for(int o=32;o>=1;o>>=1) v = fmaxf(v,__shfl_xor(v,o,64));
  return v;
}

// pe[p, 2i] = sin(p * exp(-2i*ln(10000)/48)), pe[p, 2i+1] = cos(...)
__device__ __forceinline__ float pe_val(int p, int j){   // precise (table init)
  int i = j >> 1;
  float f = expf(-0.19188209108283716f * (float)(2*i));
  float a = (float)p * f;
  return (j & 1) ? cosf(a) : sinf(a);
}
__device__ __forceinline__ float pe_fast(int p, int j){  // encoder embed
  int i = j >> 1;
  float f = __expf(-0.19188209108283716f * (float)(2*i));
  float a = (float)p * f;
  return (j & 1) ? __cosf(a) : __sinf(a);
}

// ---- packed fp16 dot: d = a.x*b.x + a.y*b.y + c (v_dot2_f32_f16) ----
typedef _Float16 h2v __attribute__((ext_vector_type(2)));
union H2U { __half2 h; h2v v; };
__device__ __forceinline__ float fdot2(__half2 a, __half2 b, float c){
#if __has_builtin(__builtin_amdgcn_fdot2)
  H2U ua, ub; ua.h=a; ub.h=b;
  return __builtin_amdgcn_fdot2(ua.v, ub.v, c, false);
#else
  float2 fa=__half22float2(a), fb=__half22float2(b);
  return fmaf(fa.y, fb.y, fmaf(fa.x, fb.x, c));
#endif
}

// 48-dot, both operands fp16 (LDS or regs), 4 accumulator chains
__device__ __forceinline__ float dot48d(const __half2* x, const __half* w){
  const __half2* w2=(const __half2*)w;
  float a0=0.f,a1=0.f,a2=0.f,a3=0.f;
  #pragma unroll
  for(int c=0;c<6;c++){
    a0=fdot2(x[4*c+0],w2[4*c+0],a0);
    a1=fdot2(x[4*c+1],w2[4*c+1],a1);
    a2=fdot2(x[4*c+2],w2[4*c+2],a2);
    a3=fdot2(x[4*c+3],w2[4*c+3],a3);
  }
  return (a0+a1)+(a2+a3);
}
// 128-dot, 8 accumulator chains
__device__ __forceinline__ float dot128d(const __half2* x, const __half* w){
  const __half2* w2=(const __half2*)w;
  float a0=0.f,a1=0.f,a2=0.f,a3=0.f,a4=0.f,a5=0.f,a6=0.f,a7=0.f;
  #pragma unroll
  for(int c=0;c<8;c++){
    a0=fdot2(x[8*c+0],w2[8*c+0],a0);
    a1=fdot2(x[8*c+1],w2[8*c+1],a1);
    a2=fdot2(x[8*c+2],w2[8*c+2],a2);
    a3=fdot2(x[8*c+3],w2[8*c+3],a3);
    a4=fdot2(x[8*c+4],w2[8*c+4],a4);
    a5=fdot2(x[8*c+5],w2[8*c+5],a5);
    a6=fdot2(x[8*c+6],w2[8*c+6],a6);
    a7=fdot2(x[8*c+7],w2[8*c+7],a7);
  }
  return ((a0+a1)+(a2+a3))+((a4+a5)+(a6+a7));
}
__device__ __forceinline__ float dot12f(const float4* x, const float4* k){
  float a=0.f;
  #pragma unroll
  for(int u=0;u<3;u++){ float4 xx=x[u], kk=k[u];
    a+=xx.x*kk.x+xx.y*kk.y+xx.z*kk.z+xx.w*kk.w; }
  return a;
}

// ---------------- K1: embed + PE -> X0 (fp32) ----------------
__global__ void k_embed(const float* __restrict__ src, const float* __restrict__ in_w,
                        const float* __restrict__ in_b, float* __restrict__ X0){
  int idx = blockIdx.x*256 + threadIdx.x;
  if (idx >= kB*kS*kD) return;
  int j = idx % kD; int bs = idx / kD; int s = bs % kS;
  float v = (src[bs] * in_w[j] + in_b[j]) * 6.928203230275509f;
  X0[idx] = v + pe_fast(s, j);
}

// ---------------- K2: encoder QKV projection, fp16 x + dot2 ----------------
__global__ void __launch_bounds__(256) k_qkv(const float* __restrict__ X,
    const float* __restrict__ wq, const float* __restrict__ bq,
    const float* __restrict__ wk, const float* __restrict__ bk,
    const float* __restrict__ wv, const float* __restrict__ bv,
    __half* __restrict__ Q, __half* __restrict__ K, __half* __restrict__ V){
  __shared__ __align__(16) __half W[3*2688];     // col stride 56 halves
  __shared__ __align__(16) float bias[3*kD];
  __shared__ __align__(16) __half2 xt2[32*24];
  int tid = threadIdx.x;
  for (int i=tid;i<3*2304;i+=256){ int m=i/2304, e=i%2304, k=e/48, j=e%48;
    const float* w = (m==0)?wq:((m==1)?wk:wv);
    W[m*2688 + j*56 + k] = __float2half(w[e]); }
  for (int i=tid;i<3*kD;i+=256){ int m=i/kD,e=i%kD;
    const float* w=(m==0)?bq:((m==1)?bk:bv); bias[i]=w[e]; }
  long row0 = (long)blockIdx.x*32;
  const float2* Xp=(const float2*)(X+row0*kD);
  for (int i=tid;i<768;i+=256){ float2 v=Xp[i]; xt2[i]=__floats2half2_rn(v.x,v.y); }
  __syncthreads();
  int r = tid>>3, c0 = tid&7;
  __half2 xr[24];
  #pragma unroll
  for(int u=0;u<24;u++) xr[u]=xt2[r*24+u];
  for (int c=c0; c<3*kD; c+=8){
    int m=c/kD, j=c%kD;
    float acc = bias[m*kD+j] + dot48d(xr, W + m*2688 + j*56);
    __half* o = (m==0)?Q:((m==1)?K:V);
    o[(row0+r)*kD+j]=__float2half(acc);
  }
}

// ---------------- K3: encoder attention — half2 K (dot2 scores), fp32 V/P ----------------
__global__ void __launch_bounds__(256) k_attn(const __half* Q, const __half* __restrict__ K,
                       const __half* __restrict__ V, __half* O){
  int b = blockIdx.x / kNH, h = blockIdx.x % kNH;
  __shared__ __align__(16) __half2 Ks2[kS*6];  // 12 KB
  __shared__ __align__(16) float   Vs[kS*kHD]; // 24 KB (fp32: P stays fp32, no overflow)
  int tid = threadIdx.x;
  long base = ((long)b*kS)*kD + h*kHD;
  for (int i=tid;i<kS*6;i+=256){ int r=i/6, c=i%6;
    Ks2[i]=*(const __half2*)&K[base+(long)r*kD+2*c]; }
  for (int i=tid;i<kS*kHD;i+=256){ int r=i/kHD, d=i%kHD;
    Vs[i]=__half2float(V[base+(long)r*kD+d]); }
  const float rs = 0.28867513459481287f;
  int q0 = tid, q1 = tid+256;
  __half2 qa2[6], qb2[6];
  {
    const __half2* qp0=(const __half2*)(Q+base+(long)q0*kD);
    const __half2* qp1=(const __half2*)(Q+base+(long)q1*kD);
    #pragma unroll
    for(int c=0;c<6;c++){ qa2[c]=qp0[c]; qb2[c]=qp1[c]; }
  }
  __syncthreads();
  float acc0[kHD], acc1[kHD];
  #pragma unroll
  for(int j=0;j<kHD;j++){ acc0[j]=0.f; acc1[j]=0.f; }
  float l0=0.f, l1=0.f;
  for(int k=0;k<kS;k++){
    const __half2* kp=Ks2+k*6;
    float sA0=0.f,sA1=0.f,sB0=0.f,sB1=0.f;
    #pragma unroll
    for(int c=0;c<3;c++){
      sA0=fdot2(qa2[2*c],kp[2*c],sA0); sA1=fdot2(qa2[2*c+1],kp[2*c+1],sA1);
      sB0=fdot2(qb2[2*c],kp[2*c],sB0); sB1=fdot2(qb2[2*c+1],kp[2*c+1],sB1);
    }
    float p0=__expf((sA0+sA1)*rs), p1=__expf((sB0+sB1)*rs);
    l0+=p0; l1+=p1;
    const float4* vp=(const float4*)(Vs+k*kHD);
    float4 va=vp[0], vb4=vp[1], vc4=vp[2];
    float vr[kHD]={va.x,va.y,va.z,va.w,vb4.x,vb4.y,vb4.z,vb4.w,vc4.x,vc4.y,vc4.z,vc4.w};
    #pragma unroll
    for(int j=0;j<kHD;j++){ acc0[j]+=p0*vr[j]; acc1[j]+=p1*vr[j]; }
  }
  float i0=1.f/l0, i1=1.f/l1;
  #pragma unroll
  for(int j=0;j<kHD;j++){
    O[base+(long)q0*kD+j]=__float2half(acc0[j]*i0);
    O[base+(long)q1*kD+j]=__float2half(acc1[j]*i1);
  }
}

// ---------------- K4: o-proj + residual + LN, dot2 ----------------
__global__ void __launch_bounds__(256) k_oproj_ln(const float* __restrict__ Xres, const __half* __restrict__ O,
      const float* __restrict__ wo, const float* __restrict__ bo,
      const float* __restrict__ g, const float* __restrict__ bb,
      __half* __restrict__ Xout){
  __shared__ __align__(16) __half W[kD*56];
  __shared__ float bsh[kD], gs[kD], bs2[kD];
  __shared__ __align__(16) float res[32*kD];
  __shared__ __align__(16) __half2 ot2[32*24];
  __shared__ float mrow[32], rstd[32];
  int tid=threadIdx.x;
  for(int i=tid;i<kD*kD;i+=256){ int k=i/48, j=i%48; W[j*56+k]=__float2half(wo[i]); }
  if(tid<kD){ bsh[tid]=bo[tid]; gs[tid]=g[tid]; bs2[tid]=bb[tid]; }
  long row0=(long)blockIdx.x*32;
  const __half2* Op=(const __half2*)(O+row0*kD);
  for(int i=tid;i<768;i+=256) ot2[i]=Op[i];
  __syncthreads();
  int r=tid>>3, c0=tid&7;
  __half2 orow[24];
  #pragma unroll
  for(int u=0;u<24;u++) orow[u]=ot2[r*24+u];
  for(int j=c0;j<kD;j+=8){
    float acc=bsh[j]+dot48d(orow, W+j*56);
    res[r*kD+j]=Xres[row0*kD + r*kD + j]+acc;
  }
  __syncthreads();
  if(tid<32){
    float s=0.f, s2=0.f;
    for(int j=0;j<kD;j++){ float v=res[tid*kD+j]; s+=v; s2+=v*v; }
    float m=s*(1.f/kD);
    mrow[tid]=m; rstd[tid]=rsqrtf(s2*(1.f/kD)-m*m+1e-5f);
  }
  __syncthreads();
  for(int i=tid;i<32*kD;i+=256){int r2=i/kD,j=i%kD;
    Xout[row0*kD+i]=__float2half((res[i]-mrow[r2])*rstd[r2]*gs[j]+bs2[j]); }
}

// ---------------- K5: FFN + residual + LN, dot2 ----------------
__global__ void __launch_bounds__(256) k_ffn_ln(const __half* __restrict__ Xin,
   const float* __restrict__ w1, const float* __restrict__ b1,
   const float* __restrict__ w2, const float* __restrict__ b2,
   const float* __restrict__ g, const float* __restrict__ bb,
   float* __restrict__ Xout){
  __shared__ __align__(16) __half W1[kFF*56];
  __shared__ __align__(16) __half W2[kD*136];
  __shared__ float b1s[kFF], b2s[kD], gs[kD], bs2[kD];
  __shared__ __align__(16) __half xt[16*kD];
  __shared__ __align__(16) __half h1h[16*kFF];
  __shared__ __align__(16) float res[16*kD];
  __shared__ float mrow[16], rstd[16];
  int tid=threadIdx.x;
  for(int i=tid;i<kD*kFF;i+=256){ int k=i/128, c=i%128; W1[c*56+k]=__float2half(w1[i]); }
  for(int i=tid;i<kFF*kD;i+=256){ int u=i/48, j=i%48; W2[j*136+u]=__float2half(w2[i]); }
  if(tid<kFF) b1s[tid]=b1[tid];
  if(tid<kD){ b2s[tid]=b2[tid]; gs[tid]=g[tid]; bs2[tid]=bb[tid]; }
  long row0=(long)blockIdx.x*16;
  const __half2* Xp=(const __half2*)(Xin+row0*kD);
  for(int i=tid;i<384;i+=256) ((__half2*)xt)[i]=Xp[i];
  __syncthreads();
  int r=tid>>4, c0=tid&15;
  {
    __half2 xr[24];
    const __half2* xp=(const __half2*)(xt + r*kD);
    #pragma unroll
    for(int u=0;u<24;u++) xr[u]=xp[u];
    for(int c=c0;c<kFF;c+=16){
      float acc=b1s[c]+dot48d(xr, W1+c*56);
      h1h[r*kFF+c]=__float2half(fmaxf(acc,0.f));
    }
  }
  __syncthreads();
  {
    const __half2* hp=(const __half2*)(h1h + r*kFF);
    for(int j=c0;j<kD;j+=16){
      float acc=b2s[j]+dot128d(hp, W2+j*136);
      res[r*kD+j]=__half2float(xt[r*kD+j])+acc;
    }
  }
  __syncthreads();
  if(tid<16){
    float s=0.f, s2=0.f;
    for(int j=0;j<kD;j++){ float v=res[tid*kD+j]; s+=v; s2+=v*v; }
    float m=s*(1.f/kD);
    mrow[tid]=m; rstd[tid]=rsqrtf(s2*(1.f/kD)-m*m+1e-5f);
  }
  __syncthreads();
  for(int i=tid;i<16*kD;i+=256){int r2=i/kD,j=i%kD;
    Xout[row0*kD+i]=(res[i]-mrow[r2])*rstd[r2]*gs[j]+bs2[j]; }
}

// ---------------- K6: cross K/V projection — K row-major [b][s][d], V transposed [b][d][s] ----------------
__global__ void __launch_bounds__(256) k_ckv(const float* __restrict__ M,
    const float* __restrict__ wk, const float* __restrict__ bk,
    const float* __restrict__ wv, const float* __restrict__ bv,
    __half* __restrict__ Kc, __half* __restrict__ Vc){
  __shared__ __align__(16) __half W[2*2688];
  __shared__ float bias[2*kD];
  __shared__ __align__(16) __half2 xt2[32*24];
  int tid=threadIdx.x;
  for(int i=tid;i<2*2304;i+=256){ int m=i/2304, e=i%2304, k=e/48, j=e%48;
    W[m*2688 + j*56 + k] = __float2half((m?wv:wk)[e]); }
  for(int i=tid;i<2*kD;i+=256){ int m=i/kD,e=i%kD; bias[i]=(m?bv:bk)[e]; }
  long row0=(long)blockIdx.x*32;
  const float2* Mp=(const float2*)(M+row0*kD);
  for(int i=tid;i<768;i+=256){ float2 v=Mp[i]; xt2[i]=__floats2half2_rn(v.x,v.y); }
  __syncthreads();
  int r=tid>>3, c0=tid&7;
  __half2 xr[24];
  #pragma unroll
  for(int u=0;u<24;u++) xr[u]=xt2[r*24+u];
  long gr=row0+r; long bb2=gr>>9; long s=gr&511;
  for(int c=c0;c<2*kD;c+=8){
    int m=c/kD, j=c%kD;
    float acc=bias[m*kD+j]+dot48d(xr, W+m*2688+j*56);
    if(m==0) Kc[(bb2*kS+s)*kD + j]=__float2half(acc);     // [b][s][d]
    else     Vc[(bb2*kD+j)*kS + s]=__float2half(acc);     // [b][d][s]
  }
}

// ---------------- K0: decoder weights -> padded FP16, column-major ----------------
// Wh halves: 6 mats 48 cols stride 56: swq@0 swk@2688 swv@5376 swo@8064 cwq@10752
// cwo@13440; w1 128 cols stride 56 @16128; w2 48 cols stride 136 @23296. Tot 29824.
__global__ void k_prep(const float* __restrict__ swq,const float* __restrict__ swk,
                       const float* __restrict__ swv,const float* __restrict__ swo,
                       const float* __restrict__ cwq,const float* __restrict__ cwo,
                       const float* __restrict__ w1,const float* __restrict__ w2,
                       __half* __restrict__ Wh){
  int idx=blockIdx.x*256+threadIdx.x;
  if(idx>=26112) return;
  if(idx<13824){
    int m=idx/2304, e=idx%2304, j=e/48, k=e%48;
    const float* w = (m==0)?swq:((m==1)?swk:((m==2)?swv:((m==3)?swo:((m==4)?cwq:cwo))));
    Wh[m*2688 + j*56 + k] = __float2half(w[k*48+j]);
  } else if(idx<19968){
    int e=idx-13824, c=e/48, k=e%48;
    Wh[16128 + c*56 + k] = __float2half(w1[k*128+c]);
  } else {
    int e=idx-19968, j=e/128, u=e%128;
    Wh[23296 + j*136 + u] = __float2half(w2[u*48+j]);
  }
}

// ---------------- K7: decoder — R10 schedule + dot2 + fp16 LDS vectors + PE table ----------------
struct DecP {
  const float *dec_start, *sbq, *sbk, *sbv, *sbo, *ln1g, *ln1b,
              *cbq, *cbo, *ln2g, *ln2b, *fb1, *fb2, *ln3g, *ln3b, *ow, *ob;
};

__global__ void __launch_bounds__(256,1) k_dec(const __half* __restrict__ KT,
    const __half* __restrict__ VT, const __half* __restrict__ Wg, DecP P,
    float* __restrict__ out){
  __shared__ __align__(16) __half Wl[29824];       // fp16 weights, 58.25 KB
  __shared__ __align__(16) float Kh[kNH*kT*kHD];   // self-attn K cache fp32, 12 KB
  __shared__ __align__(16) float Vh[kNH*kT*kHD];
  __shared__ __align__(16) float qS[kNH*16];
  __shared__ __align__(16) __half xvH[kD], soH[kD], h1H[kD], cqH[kD], covH[kD], h2H[kD];
  __shared__ __align__(16) __half f1H[kFF];
  __shared__ __align__(16) float peT[kT*kD];       // PE table, 12 KB (init once)
  int tid=threadIdx.x, b=blockIdx.x, wave=tid>>6, lane=tid&63;
  const float rs=0.28867513459481287f;

  for(int i=tid;i<29824/8;i+=256) ((float4*)Wl)[i]=((const float4*)Wg)[i];
  for(int i=tid;i<kT*kD;i+=256){ int tt=i/kD, j=i%kD; peT[i]=pe_val(tt,j); }

  // per-lane constants (R10 wave-specialized layout)
  float cur=0, c_bo=0,c_cbq=0,c_cbo=0,c_fb2=0;
  float g1=0,bb1=0,g2=0,bb2=0,g3=0,bb3=0,c_ow=0;
  if(wave==0 && lane<kD){
    cur=P.dec_start[lane];
    c_bo=P.sbo[lane]; c_cbq=P.cbq[lane]; c_cbo=P.cbo[lane]; c_fb2=P.fb2[lane];
    g1=P.ln1g[lane]; bb1=P.ln1b[lane];
    g2=P.ln2g[lane]; bb2=P.ln2b[lane];
    g3=P.ln3g[lane]; bb3=P.ln3b[lane];
    c_ow=P.ow[lane];
  }
  float c_qkvb=0;
  if(wave>=1 && lane<kD)
    c_qkvb = ((wave==1)?P.sbq:((wave==2)?P.sbk:P.sbv))[lane];
  float c_fb1=0;
  if(wave<2) c_fb1=P.fb1[wave*64+lane];
  float c_ob=P.ob[0];

  // cross-attn K/V resident in registers: head = wave, 4 key-PAIRS per lane
  // Kc layout [b][s][d]; Vc layout [b][d][s] read as half2 pairs along s.
  __half2 Kr2[4][2][6], Vr2[4][kHD];   // 48 + 48 VGPRs
  {
    const __half* Kb = KT + (long)b*kS*kD;
    const __half2* Vb = (const __half2*)VT + (long)b*kD*(kS/2);
    #pragma unroll
    for(int i=0;i<4;i++){
      int sp = lane + 64*i;
      #pragma unroll
      for(int e=0;e<2;e++){
        const __half2* kp=(const __half2*)(Kb + (long)(2*sp+e)*kD + wave*kHD);
        #pragma unroll
        for(int c=0;c<6;c++) Kr2[i][e][c]=kp[c];
      }
      #pragma unroll
      for(int u=0;u<kHD;u++) Vr2[i][u]=Vb[(wave*kHD+u)*(kS/2)+sp];
    }
  }
  __syncthreads();

  float h1=0, h2=0, xv=0;
  for(int t=0;t<kT;t++){
    // stage0: wave0 publishes x (fp32 in reg, fp16 to LDS)
    if(wave==0 && lane<kD){ xv=cur+peT[t*kD+lane]; xvH[lane]=__float2half(xv); }
    __syncthreads();                                   // B0
    // stage1: waves 1..3 compute q/k/v (m = wave-1)
    if(wave>=1 && lane<kD){
      int m=wave-1;
      float a=c_qkvb+dot48d((const __half2*)xvH, Wl + m*2688 + lane*56);
      int hh=lane/kHD, dd=lane%kHD;
      if(m==0) qS[hh*16+dd]=a;
      else if(m==1) Kh[(hh*kT+t)*kHD+dd]=a;
      else          Vh[(hh*kT+t)*kHD+dd]=a;
    }
    __syncthreads();                                   // B1
    // stage2: self-attn (fp32), head = wave, lane = key
    {
      float p=0.f, pv[kHD];
      #pragma unroll
      for(int u=0;u<kHD;u++) pv[u]=0.f;
      if(lane<=t){
        float s=dot12f((const float4*)(qS+wave*16),
                       (const float4*)(Kh+(wave*kT+lane)*kHD))*rs;
        p=__expf(s);
        const float4* vp=(const float4*)(Vh+(wave*kT+lane)*kHD);
        float4 v0=vp[0], v1=vp[1], v2=vp[2];
        float vr[kHD]={v0.x,v0.y,v0.z,v0.w,v1.x,v1.y,v1.z,v1.w,v2.x,v2.y,v2.z,v2.w};
        #pragma unroll
        for(int u=0;u<kHD;u++) pv[u]=p*vr[u];
      }
      float l=wsum(p);
      #pragma unroll
      for(int u=0;u<kHD;u++) pv[u]=wsum(pv[u]);
      if(lane==0){
        float inv=1.f/l;
        #pragma unroll
        for(int u=0;u<6;u++)
          ((__half2*)soH)[wave*6+u]=__floats2half2_rn(pv[2*u]*inv, pv[2*u+1]*inv);
      }
    }
    __syncthreads();                                   // B2
    // stage3: wave0 — self o-proj + residual + LN1 + cross-q
    if(wave==0){
      float rr=0.f;
      if(lane<kD)
        rr=xv+c_bo+dot48d((const __half2*)soH, Wl+8064+lane*56);
      float s1=wsum(rr), s2=wsum(rr*rr);
      float mean=s1*(1.f/48.f);
      float rstd=rsqrtf(s2*(1.f/48.f)-mean*mean+1e-5f);
      h1=0;
      if(lane<kD){ h1=(rr-mean)*rstd*g1+bb1; h1H[lane]=__float2half(h1); }
      wsync();
      if(lane<kD)
        cqH[lane]=__float2half(c_cbq+dot48d((const __half2*)h1H, Wl+10752+lane*56));
    }
    __syncthreads();                                   // B3
    // stage4: cross-attn from registers, head = wave; max-sub for fp16 P
    {
      __half2 q2[6];
      #pragma unroll
      for(int c=0;c<6;c++) q2[c]=((const __half2*)cqH)[wave*6+c];
      float s[8];
      #pragma unroll
      for(int i=0;i<4;i++){
        #pragma unroll
        for(int e=0;e<2;e++){
          float a0=0.f,a1=0.f;
          const __half2* kp=Kr2[i][e];
          a0=fdot2(q2[0],kp[0],a0); a1=fdot2(q2[1],kp[1],a1);
          a0=fdot2(q2[2],kp[2],a0); a1=fdot2(q2[3],kp[3],a1);
          a0=fdot2(q2[4],kp[4],a0); a1=fdot2(q2[5],kp[5],a1);
          s[2*i+e]=(a0+a1)*rs;
        }
      }
      float mloc=s[0];
      #pragma unroll
      for(int j=1;j<8;j++) mloc=fmaxf(mloc,s[j]);
      float M=wmax(mloc);
      float p[8], l=0.f;
      #pragma unroll
      for(int j=0;j<8;j++){ p[j]=__expf(s[j]-M); l+=p[j]; }
      l=wsum(l);
      float inv=1.f/l;
      __half2 ph[4];
      #pragma unroll
      for(int i=0;i<4;i++) ph[i]=__floats2half2_rn(p[2*i],p[2*i+1]);
      float acc[kHD];
      #pragma unroll
      for(int u=0;u<kHD;u++) acc[u]=0.f;
      #pragma unroll
      for(int i=0;i<4;i++){
        #pragma unroll
        for(int u=0;u<kHD;u++) acc[u]=fdot2(ph[i],Vr2[i][u],acc[u]);
      }
      #pragma unroll
      for(int u=0;u<kHD;u++) acc[u]=wsum(acc[u]);
      if(lane==0){
        #pragma unroll
        for(int u=0;u<6;u++)
          ((__half2*)covH)[wave*6+u]=__floats2half2_rn(acc[2*u]*inv, acc[2*u+1]*inv);
      }
    }
    __syncthreads();                                   // B4
    // stage5: wave0 — cross o-proj + residual + LN2
    if(wave==0){
      float rr=0.f;
      if(lane<kD)
        rr=h1+c_cbo+dot48d((const __half2*)covH, Wl+13440+lane*56);
      float s1=wsum(rr), s2=wsum(rr*rr);
      float mean=s1*(1.f/48.f);
      float rstd=rsqrtf(s2*(1.f/48.f)-mean*mean+1e-5f);
      h2=0;
      if(lane<kD){ h2=(rr-mean)*rstd*g2+bb2; h2H[lane]=__float2half(h2); }
    }
    __syncthreads();                                   // B5
    // stage6: FFN1 on waves 0,1 (col = wave*64 + lane)
    if(wave<2){
      int col=wave*64+lane;
      float a=c_fb1+dot48d((const __half2*)h2H, Wl+16128+col*56);
      f1H[col]=__float2half(fmaxf(a,0.f));
    }
    __syncthreads();                                   // B6
    // stage7: wave0 — FFN2 + residual + LN3 + output
    if(wave==0){
      float rr=0.f;
      if(lane<kD)
        rr=h2+c_fb2+dot128d((const __half2*)f1H, Wl+23296+lane*136);
      float s1=wsum(rr), s2=wsum(rr*rr);
      float mean=s1*(1.f/48.f);
      float rstd=rsqrtf(s2*(1.f/48.f)-mean*mean+1e-5f);
      float cv=0.f;
      if(lane<kD){ cv=(rr-mean)*rstd*g3+bb3; cur=cv; }
      float y=wsum(cv*c_ow);
      if(lane==0) out[b*kT+t]=y+c_ob;
    }
  }
}

extern "C" void kernel_launch(void* const* d_in, const int* in_sizes, int n_in,
                              void* d_out, int out_size, void* d_ws, size_t ws_size,
                              hipStream_t stream){
  // ws: Wh fp16 (reserve 65536 B), A fp32 NB, H1/H2/H3 fp16 NB each (~31.5 MiB).
  float* ws = (float*)d_ws;
  __half* Wh = (__half*)ws;
  const size_t NB = (size_t)kB*kS*kD;     // 3,145,728
  float*  A  = ws + 16384;
  __half* H1 = (__half*)(A + NB);
  __half* H2 = H1 + NB;
  __half* H3 = H2 + NB;

  k_embed<<<(kB*kS*kD+255)/256,256,0,stream>>>((const float*)d_in[0],(const float*)d_in[1],(const float*)d_in[2],A);
  k_qkv  <<<(kB*kS)/32,256,0,stream>>>(A,(const float*)d_in[4],(const float*)d_in[5],(const float*)d_in[6],
                                       (const float*)d_in[7],(const float*)d_in[8],(const float*)d_in[9],H1,H2,H3);
  k_attn <<<kB*kNH,256,0,stream>>>(H1,H2,H3,H1);
  k_oproj_ln<<<(kB*kS)/32,256,0,stream>>>(A,H1,(const float*)d_in[10],(const float*)d_in[11],
                                          (const float*)d_in[12],(const float*)d_in[13],H2);
  k_ffn_ln  <<<(kB*kS)/16,256,0,stream>>>(H2,(const float*)d_in[14],(const float*)d_in[15],(const float*)d_in[16],
                                          (const float*)d_in[17],(const float*)d_in[18],(const float*)d_in[19],A);
  k_ckv     <<<(kB*kS)/32,256,0,stream>>>(A,(const float*)d_in[32],(const float*)d_in[33],
                                          (const float*)d_in[34],(const float*)d_in[35],H1,H3);
  k_prep    <<<(26112+255)/256,256,0,stream>>>((const float*)d_in[20],(const float*)d_in[22],(const float*)d_in[24],
                                               (const float*)d_in[26],(const float*)d_in[30],(const float*)d_in[36],
                                               (const float*)d_in[40],(const float*)d_in[42],Wh);
  DecP P;
  P.dec_start=(const float*)d_in[3];
  P.sbq=(const float*)d_in[21]; P.sbk=(const float*)d_in[23]; P.sbv=(const float*)d_in[25]; P.sbo=(const float*)d_in[27];
  P.ln1g=(const float*)d_in[28]; P.ln1b=(const float*)d_in[29];
  P.cbq=(const float*)d_in[31]; P.cbo=(const float*)d_in[37];
  P.ln2g=(const float*)d_in[38]; P.ln2b=(const float*)d_in[39];
  P.fb1=(const float*)d_in[41]; P.fb2=(const float*)d_in[43];
  P.ln3g=(const float*)d_in[44]; P.ln3b=(const float*)d_in[45];
  P.ow=(const float*)d_in[46]; P.ob=(const float*)d_in[47];
  k_dec<<<kB,256,0,stream>>>(H1,H3,Wh,P,(float*)d_out);
}

// Round 3
// 671.682 us; speedup vs baseline: 1.3550x; 1.0250x over previous
//
#include <hip/hip_runtime.h>
#include <hip/hip_bf16.h>
#include <hip/hip_fp16.h>

// Inputs/outputs are FP32 (verified R3/R6).
// R10 lesson: KV-in-regs OR weights-in-regs — never both (VGPR cap 256 -> spill).
// R11 lesson: redundant all-wave broadcast stages LOSE (4x LDS traffic > 3 barriers).
// R12 lesson: v_dot2 + fp16 LDS vectors cut k_dec 450->335; VALUBusy fell to 8% ->
//             chain is pure dependent-latency. R13: overlap two independent batch
//             chains per block (chain0 waves 0-3, chain1 waves 4-7 share SIMDs) +
//             DPP-based wave reductions (VALU-speed, vs ds_bpermute ~240cy chains).

constexpr int kB  = 128;
constexpr int kS  = 512;
constexpr int kT  = 64;
constexpr int kD  = 48;
constexpr int kFF = 128;
constexpr int kNH = 4;
constexpr int kHD = 12;

__device__ __forceinline__ void wsync(){
  __builtin_amdgcn_wave_barrier();
  asm volatile("" ::: "memory");
}

// ---- DPP wave64 reductions (VALU-speed; ds_bpermute chains were ~240 cy) ----
template<int CTRL,int RM,int BM,bool BC>
__device__ __forceinline__ float dppmov(float x, float old){
  return __builtin_bit_cast(float, __builtin_amdgcn_update_dpp(
      __builtin_bit_cast(int, old), __builtin_bit_cast(int, x), CTRL, RM, BM, BC));
}
// sum across 64 lanes, result uniform in all lanes
__device__ __forceinline__ float wsum(float x){
  x += dppmov<0x111,0xf,0xf,true>(x, 0.f);   // row_shr:1
  x += dppmov<0x112,0xf,0xf,true>(x, 0.f);   // row_shr:2
  x += dppmov<0x114,0xf,0xf,true>(x, 0.f);   // row_shr:4
  x += dppmov<0x118,0xf,0xf,true>(x, 0.f);   // row_shr:8
  x += dppmov<0x142,0xa,0xf,true>(x, 0.f);   // row_bcast:15 -> rows 1,3
  x += dppmov<0x143,0xc,0xf,true>(x, 0.f);   // row_bcast:31 -> rows 2,3
  return __builtin_bit_cast(float, __builtin_amdgcn_readlane(__builtin_bit_cast(int, x), 63));
}
__device__ __forceinline__ float wmax(float x){
  const float NI = -3.4e38f;
  x = fmaxf(x, dppmov<0x111,0xf,0xf,false>(x, NI));
  x = fmaxf(x, dppmov<0x112,0xf,0xf,false>(x, NI));
  x = fmaxf(x, dppmov<0x114,0xf,0xf,false>(x, NI));
  x = fmaxf(x, dppmov<0x118,0xf,0xf,false>(x, NI));
  x = fmaxf(x, dppmov<0x142,0xa,0xf,false>(x, NI));
  x = fmaxf(x, dppmov<0x143,0xc,0xf,false>(x, NI));
  return __builtin_bit_cast(float, __builtin_amdgcn_readlane(__builtin_bit_cast(int, x), 63));
}

// pe[p, 2i] = sin(p * exp(-2i*ln(10000)/48)), pe[p, 2i+1] = cos(...)
__device__ __forceinline__ float pe_val(int p, int j){   // precise (table init)
  int i = j >> 1;
  float f = expf(-0.19188209108283716f * (float)(2*i));
  float a = (float)p * f;
  return (j & 1) ? cosf(a) : sinf(a);
}
__device__ __forceinline__ float pe_fast(int p, int j){  // encoder embed
  int i = j >> 1;
  float f = __expf(-0.19188209108283716f * (float)(2*i));
  float a = (float)p * f;
  return (j & 1) ? __cosf(a) : __sinf(a);
}

// ---- packed fp16 dot: d = a.x*b.x + a.y*b.y + c (v_dot2_f32_f16) ----
typedef _Float16 h2v __attribute__((ext_vector_type(2)));
union H2U { __half2 h; h2v v; };
__device__ __forceinline__ float fdot2(__half2 a, __half2 b, float c){
#if __has_builtin(__builtin_amdgcn_fdot2)
  H2U ua, ub; ua.h=a; ub.h=b;
  return __builtin_amdgcn_fdot2(ua.v, ub.v, c, false);
#else
  float2 fa=__half22float2(a), fb=__half22float2(b);
  return fmaf(fa.y, fb.y, fmaf(fa.x, fb.x, c));
#endif
}

// 48-dot, both operands fp16 (LDS or regs), 4 accumulator chains
__device__ __forceinline__ float dot48d(const __half2* x, const __half* w){
  const __half2* w2=(const __half2*)w;
  float a0=0.f,a1=0.f,a2=0.f,a3=0.f;
  #pragma unroll
  for(int c=0;c<6;c++){
    a0=fdot2(x[4*c+0],w2[4*c+0],a0);
    a1=fdot2(x[4*c+1],w2[4*c+1],a1);
    a2=fdot2(x[4*c+2],w2[4*c+2],a2);
    a3=fdot2(x[4*c+3],w2[4*c+3],a3);
  }
  return (a0+a1)+(a2+a3);
}
// 128-dot, 8 accumulator chains
__device__ __forceinline__ float dot128d(const __half2* x, const __half* w){
  const __half2* w2=(const __half2*)w;
  float a0=0.f,a1=0.f,a2=0.f,a3=0.f,a4=0.f,a5=0.f,a6=0.f,a7=0.f;
  #pragma unroll
  for(int c=0;c<8;c++){
    a0=fdot2(x[8*c+0],w2[8*c+0],a0);
    a1=fdot2(x[8*c+1],w2[8*c+1],a1);
    a2=fdot2(x[8*c+2],w2[8*c+2],a2);
    a3=fdot2(x[8*c+3],w2[8*c+3],a3);
    a4=fdot2(x[8*c+4],w2[8*c+4],a4);
    a5=fdot2(x[8*c+5],w2[8*c+5],a5);
    a6=fdot2(x[8*c+6],w2[8*c+6],a6);
    a7=fdot2(x[8*c+7],w2[8*c+7],a7);
  }
  return ((a0+a1)+(a2+a3))+((a4+a5)+(a6+a7));
}
__device__ __forceinline__ float dot12f(const float4* x, const float4* k){
  float a=0.f;
  #pragma unroll
  for(int u=0;u<3;u++){ float4 xx=x[u], kk=k[u];
    a+=xx.x*kk.x+xx.y*kk.y+xx.z*kk.z+xx.w*kk.w; }
  return a;
}

// ---------------- K1: embed + PE -> X0 (fp32) ----------------
__global__ void k_embed(const float* __restrict__ src, const float* __restrict__ in_w,
                        const float* __restrict__ in_b, float* __restrict__ X0){
  int idx = blockIdx.x*256 + threadIdx.x;
  if (idx >= kB*kS*kD) return;
  int j = idx % kD; int bs = idx / kD; int s = bs % kS;
  float v = (src[bs] * in_w[j] + in_b[j]) * 6.928203230275509f;
  X0[idx] = v + pe_fast(s, j);
}

// ---------------- K2: encoder QKV projection, fp16 x + dot2 ----------------
__global__ void __launch_bounds__(256) k_qkv(const float* __restrict__ X,
    const float* __restrict__ wq, const float* __restrict__ bq,
    const float* __restrict__ wk, const float* __restrict__ bk,
    const float* __restrict__ wv, const float* __restrict__ bv,
    __half* __restrict__ Q, __half* __restrict__ K, __half* __restrict__ V){
  __shared__ __align__(16) __half W[3*2688];     // col stride 56 halves
  __shared__ __align__(16) float bias[3*kD];
  __shared__ __align__(16) __half2 xt2[32*24];
  int tid = threadIdx.x;
  for (int i=tid;i<3*2304;i+=256){ int m=i/2304, e=i%2304, k=e/48, j=e%48;
    const float* w = (m==0)?wq:((m==1)?wk:wv);
    W[m*2688 + j*56 + k] = __float2half(w[e]); }
  for (int i=tid;i<3*kD;i+=256){ int m=i/kD,e=i%kD;
    const float* w=(m==0)?bq:((m==1)?bk:bv); bias[i]=w[e]; }
  long row0 = (long)blockIdx.x*32;
  const float2* Xp=(const float2*)(X+row0*kD);
  for (int i=tid;i<768;i+=256){ float2 v=Xp[i]; xt2[i]=__floats2half2_rn(v.x,v.y); }
  __syncthreads();
  int r = tid>>3, c0 = tid&7;
  __half2 xr[24];
  #pragma unroll
  for(int u=0;u<24;u++) xr[u]=xt2[r*24+u];
  for (int c=c0; c<3*kD; c+=8){
    int m=c/kD, j=c%kD;
    float acc = bias[m*kD+j] + dot48d(xr, W + m*2688 + j*56);
    __half* o = (m==0)?Q:((m==1)?K:V);
    o[(row0+r)*kD+j]=__float2half(acc);
  }
}

// ---------------- K3: encoder attention — half2 K (dot2 scores), fp32 V/P ----------------
__global__ void __launch_bounds__(256) k_attn(const __half* Q, const __half* __restrict__ K,
                       const __half* __restrict__ V, __half* O){
  int b = blockIdx.x / kNH, h = blockIdx.x % kNH;
  __shared__ __align__(16) __half2 Ks2[kS*6];  // 12 KB
  __shared__ __align__(16) float   Vs[kS*kHD]; // 24 KB (fp32: P stays fp32, no overflow)
  int tid = threadIdx.x;
  long base = ((long)b*kS)*kD + h*kHD;
  for (int i=tid;i<kS*6;i+=256){ int r=i/6, c=i%6;
    Ks2[i]=*(const __half2*)&K[base+(long)r*kD+2*c]; }
  for (int i=tid;i<kS*kHD;i+=256){ int r=i/kHD, d=i%kHD;
    Vs[i]=__half2float(V[base+(long)r*kD+d]); }
  const float rs = 0.28867513459481287f;
  int q0 = tid, q1 = tid+256;
  __half2 qa2[6], qb2[6];
  {
    const __half2* qp0=(const __half2*)(Q+base+(long)q0*kD);
    const __half2* qp1=(const __half2*)(Q+base+(long)q1*kD);
    #pragma unroll
    for(int c=0;c<6;c++){ qa2[c]=qp0[c]; qb2[c]=qp1[c]; }
  }
  __syncthreads();
  float acc0[kHD], acc1[kHD];
  #pragma unroll
  for(int j=0;j<kHD;j++){ acc0[j]=0.f; acc1[j]=0.f; }
  float l0=0.f, l1=0.f;
  for(int k=0;k<kS;k++){
    const __half2* kp=Ks2+k*6;
    float sA0=0.f,sA1=0.f,sB0=0.f,sB1=0.f;
    #pragma unroll
    for(int c=0;c<3;c++){
      sA0=fdot2(qa2[2*c],kp[2*c],sA0); sA1=fdot2(qa2[2*c+1],kp[2*c+1],sA1);
      sB0=fdot2(qb2[2*c],kp[2*c],sB0); sB1=fdot2(qb2[2*c+1],kp[2*c+1],sB1);
    }
    float p0=__expf((sA0+sA1)*rs), p1=__expf((sB0+sB1)*rs);
    l0+=p0; l1+=p1;
    const float4* vp=(const float4*)(Vs+k*kHD);
    float4 va=vp[0], vb4=vp[1], vc4=vp[2];
    float vr[kHD]={va.x,va.y,va.z,va.w,vb4.x,vb4.y,vb4.z,vb4.w,vc4.x,vc4.y,vc4.z,vc4.w};
    #pragma unroll
    for(int j=0;j<kHD;j++){ acc0[j]+=p0*vr[j]; acc1[j]+=p1*vr[j]; }
  }
  float i0=1.f/l0, i1=1.f/l1;
  #pragma unroll
  for(int j=0;j<kHD;j++){
    O[base+(long)q0*kD+j]=__float2half(acc0[j]*i0);
    O[base+(long)q1*kD+j]=__float2half(acc1[j]*i1);
  }
}

// ---------------- K4: o-proj + residual + LN, dot2 ----------------
__global__ void __launch_bounds__(256) k_oproj_ln(const float* __restrict__ Xres, const __half* __restrict__ O,
      const float* __restrict__ wo, const float* __restrict__ bo,
      const float* __restrict__ g, const float* __restrict__ bb,
      __half* __restrict__ Xout){
  __shared__ __align__(16) __half W[kD*56];
  __shared__ float bsh[kD], gs[kD], bs2[kD];
  __shared__ __align__(16) float res[32*kD];
  __shared__ __align__(16) __half2 ot2[32*24];
  __shared__ float mrow[32], rstd[32];
  int tid=threadIdx.x;
  for(int i=tid;i<kD*kD;i+=256){ int k=i/48, j=i%48; W[j*56+k]=__float2half(wo[i]); }
  if(tid<kD){ bsh[tid]=bo[tid]; gs[tid]=g[tid]; bs2[tid]=bb[tid]; }
  long row0=(long)blockIdx.x*32;
  const __half2* Op=(const __half2*)(O+row0*kD);
  for(int i=tid;i<768;i+=256) ot2[i]=Op[i];
  __syncthreads();
  int r=tid>>3, c0=tid&7;
  __half2 orow[24];
  #pragma unroll
  for(int u=0;u<24;u++) orow[u]=ot2[r*24+u];
  for(int j=c0;j<kD;j+=8){
    float acc=bsh[j]+dot48d(orow, W+j*56);
    res[r*kD+j]=Xres[row0*kD + r*kD + j]+acc;
  }
  __syncthreads();
  if(tid<32){
    float s=0.f, s2=0.f;
    for(int j=0;j<kD;j++){ float v=res[tid*kD+j]; s+=v; s2+=v*v; }
    float m=s*(1.f/kD);
    mrow[tid]=m; rstd[tid]=rsqrtf(s2*(1.f/kD)-m*m+1e-5f);
  }
  __syncthreads();
  for(int i=tid;i<32*kD;i+=256){int r2=i/kD,j=i%kD;
    Xout[row0*kD+i]=__float2half((res[i]-mrow[r2])*rstd[r2]*gs[j]+bs2[j]); }
}

// ---------------- K5: FFN + residual + LN, dot2 ----------------
__global__ void __launch_bounds__(256) k_ffn_ln(const __half* __restrict__ Xin,
   const float* __restrict__ w1, const float* __restrict__ b1,
   const float* __restrict__ w2, const float* __restrict__ b2,
   const float* __restrict__ g, const float* __restrict__ bb,
   float* __restrict__ Xout){
  __shared__ __align__(16) __half W1[kFF*56];
  __shared__ __align__(16) __half W2[kD*136];
  __shared__ float b1s[kFF], b2s[kD], gs[kD], bs2[kD];
  __shared__ __align__(16) __half xt[16*kD];
  __shared__ __align__(16) __half h1h[16*kFF];
  __shared__ __align__(16) float res[16*kD];
  __shared__ float mrow[16], rstd[16];
  int tid=threadIdx.x;
  for(int i=tid;i<kD*kFF;i+=256){ int k=i/128, c=i%128; W1[c*56+k]=__float2half(w1[i]); }
  for(int i=tid;i<kFF*kD;i+=256){ int u=i/48, j=i%48; W2[j*136+u]=__float2half(w2[i]); }
  if(tid<kFF) b1s[tid]=b1[tid];
  if(tid<kD){ b2s[tid]=b2[tid]; gs[tid]=g[tid]; bs2[tid]=bb[tid]; }
  long row0=(long)blockIdx.x*16;
  const __half2* Xp=(const __half2*)(Xin+row0*kD);
  for(int i=tid;i<384;i+=256) ((__half2*)xt)[i]=Xp[i];
  __syncthreads();
  int r=tid>>4, c0=tid&15;
  {
    __half2 xr[24];
    const __half2* xp=(const __half2*)(xt + r*kD);
    #pragma unroll
    for(int u=0;u<24;u++) xr[u]=xp[u];
    for(int c=c0;c<kFF;c+=16){
      float acc=b1s[c]+dot48d(xr, W1+c*56);
      h1h[r*kFF+c]=__float2half(fmaxf(acc,0.f));
    }
  }
  __syncthreads();
  {
    const __half2* hp=(const __half2*)(h1h + r*kFF);
    for(int j=c0;j<kD;j+=16){
      float acc=b2s[j]+dot128d(hp, W2+j*136);
      res[r*kD+j]=__half2float(xt[r*kD+j])+acc;
    }
  }
  __syncthreads();
  if(tid<16){
    float s=0.f, s2=0.f;
    for(int j=0;j<kD;j++){ float v=res[tid*kD+j]; s+=v; s2+=v*v; }
    float m=s*(1.f/kD);
    mrow[tid]=m; rstd[tid]=rsqrtf(s2*(1.f/kD)-m*m+1e-5f);
  }
  __syncthreads();
  for(int i=tid;i<16*kD;i+=256){int r2=i/kD,j=i%kD;
    Xout[row0*kD+i]=(res[i]-mrow[r2])*rstd[r2]*gs[j]+bs2[j]; }
}

// ---------------- K6: cross K/V projection — K row-major [b][s][d], V transposed [b][d][s] ----------------
__global__ void __launch_bounds__(256) k_ckv(const float* __restrict__ M,
    const float* __restrict__ wk, const float* __restrict__ bk,
    const float* __restrict__ wv, const float* __restrict__ bv,
    __half* __restrict__ Kc, __half* __restrict__ Vc){
  __shared__ __align__(16) __half W[2*2688];
  __shared__ float bias[2*kD];
  __shared__ __align__(16) __half2 xt2[32*24];
  int tid=threadIdx.x;
  for(int i=tid;i<2*2304;i+=256){ int m=i/2304, e=i%2304, k=e/48, j=e%48;
    W[m*2688 + j*56 + k] = __float2half((m?wv:wk)[e]); }
  for(int i=tid;i<2*kD;i+=256){ int m=i/kD,e=i%kD; bias[i]=(m?bv:bk)[e]; }
  long row0=(long)blockIdx.x*32;
  const float2* Mp=(const float2*)(M+row0*kD);
  for(int i=tid;i<768;i+=256){ float2 v=Mp[i]; xt2[i]=__floats2half2_rn(v.x,v.y); }
  __syncthreads();
  int r=tid>>3, c0=tid&7;
  __half2 xr[24];
  #pragma unroll
  for(int u=0;u<24;u++) xr[u]=xt2[r*24+u];
  long gr=row0+r; long bb2=gr>>9; long s=gr&511;
  for(int c=c0;c<2*kD;c+=8){
    int m=c/kD, j=c%kD;
    float acc=bias[m*kD+j]+dot48d(xr, W+m*2688+j*56);
    if(m==0) Kc[(bb2*kS+s)*kD + j]=__float2half(acc);     // [b][s][d]
    else     Vc[(bb2*kD+j)*kS + s]=__float2half(acc);     // [b][d][s]
  }
}

// ---------------- K0: decoder weights -> padded FP16, column-major ----------------
// Wh halves: 6 mats 48 cols stride 56: swq@0 swk@2688 swv@5376 swo@8064 cwq@10752
// cwo@13440; w1 128 cols stride 56 @16128; w2 48 cols stride 136 @23296. Tot 29824.
__global__ void k_prep(const float* __restrict__ swq,const float* __restrict__ swk,
                       const float* __restrict__ swv,const float* __restrict__ swo,
                       const float* __restrict__ cwq,const float* __restrict__ cwo,
                       const float* __restrict__ w1,const float* __restrict__ w2,
                       __half* __restrict__ Wh){
  int idx=blockIdx.x*256+threadIdx.x;
  if(idx>=26112) return;
  if(idx<13824){
    int m=idx/2304, e=idx%2304, j=e/48, k=e%48;
    const float* w = (m==0)?swq:((m==1)?swk:((m==2)?swv:((m==3)?swo:((m==4)?cwq:cwo))));
    Wh[m*2688 + j*56 + k] = __float2half(w[k*48+j]);
  } else if(idx<19968){
    int e=idx-13824, c=e/48, k=e%48;
    Wh[16128 + c*56 + k] = __float2half(w1[k*128+c]);
  } else {
    int e=idx-19968, j=e/128, u=e%128;
    Wh[23296 + j*136 + u] = __float2half(w2[u*48+j]);
  }
}

// ---------------- K7: decoder — R13: 2 chains/block (8 waves), DPP reductions ----------------
struct DecP {
  const float *dec_start, *sbq, *sbk, *sbv, *sbo, *ln1g, *ln1b,
              *cbq, *cbo, *ln2g, *ln2b, *fb1, *fb2, *ln3g, *ln3b, *ow, *ob;
};

__global__ void __launch_bounds__(512,1) k_dec(const __half* __restrict__ KT,
    const __half* __restrict__ VT, const __half* __restrict__ Wg, DecP P,
    float* __restrict__ out){
  __shared__ __align__(16) __half Wl[29824];          // fp16 weights, 58.25 KB (shared)
  __shared__ __align__(16) float peT[kT*kD];          // PE table, 12 KB (shared)
  __shared__ __align__(16) float Kh[2][kNH*kT*kHD];   // per-chain self-K cache, 2x12 KB
  __shared__ __align__(16) float Vh[2][kNH*kT*kHD];
  __shared__ __align__(16) float qS[2][kNH*16];
  __shared__ __align__(16) __half xvH[2][kD], soH[2][kD], h1H[2][kD],
                                  cqH[2][kD], covH[2][kD], h2H[2][kD];
  __shared__ __align__(16) __half f1H[2][kFF];
  int tid=threadIdx.x;
  int chain = tid>>8, ctid = tid&255, wave=ctid>>6, lane=ctid&63;
  int b = blockIdx.x*2 + chain;
  const float rs=0.28867513459481287f;

  for(int i=tid;i<29824/8;i+=512) ((float4*)Wl)[i]=((const float4*)Wg)[i];
  for(int i=tid;i<kT*kD;i+=512){ int tt=i/kD, j=i%kD; peT[i]=pe_val(tt,j); }

  // per-lane constants (chain-local wave-specialized layout)
  float cur=0, c_bo=0,c_cbq=0,c_cbo=0,c_fb2=0;
  float g1=0,bb1=0,g2=0,bb2=0,g3=0,bb3=0,c_ow=0;
  if(wave==0 && lane<kD){
    cur=P.dec_start[lane];
    c_bo=P.sbo[lane]; c_cbq=P.cbq[lane]; c_cbo=P.cbo[lane]; c_fb2=P.fb2[lane];
    g1=P.ln1g[lane]; bb1=P.ln1b[lane];
    g2=P.ln2g[lane]; bb2=P.ln2b[lane];
    g3=P.ln3g[lane]; bb3=P.ln3b[lane];
    c_ow=P.ow[lane];
  }
  float c_qkvb=0;
  if(wave>=1 && lane<kD)
    c_qkvb = ((wave==1)?P.sbq:((wave==2)?P.sbk:P.sbv))[lane];
  float c_fb1=0;
  if(wave<2) c_fb1=P.fb1[wave*64+lane];
  float c_ob=P.ob[0];

  // cross-attn K/V resident in registers: head = wave, 4 key-PAIRS per lane
  // Kc layout [b][s][d]; Vc layout [b][d][s] read as half2 pairs along s.
  __half2 Kr2[4][2][6], Vr2[4][kHD];   // 48 + 48 VGPRs
  {
    const __half* Kb = KT + (long)b*kS*kD;
    const __half2* Vb = (const __half2*)VT + (long)b*kD*(kS/2);
    #pragma unroll
    for(int i=0;i<4;i++){
      int sp = lane + 64*i;
      #pragma unroll
      for(int e=0;e<2;e++){
        const __half2* kp=(const __half2*)(Kb + (long)(2*sp+e)*kD + wave*kHD);
        #pragma unroll
        for(int c=0;c<6;c++) Kr2[i][e][c]=kp[c];
      }
      #pragma unroll
      for(int u=0;u<kHD;u++) Vr2[i][u]=Vb[(wave*kHD+u)*(kS/2)+sp];
    }
  }
  __syncthreads();

  float h1=0, h2=0, xv=0;
  for(int t=0;t<kT;t++){
    // stage0: each chain's wave0 publishes x (fp32 in reg, fp16 to LDS)
    if(wave==0 && lane<kD){ xv=cur+peT[t*kD+lane]; xvH[chain][lane]=__float2half(xv); }
    __syncthreads();                                   // B0
    // stage1: waves 1..3 compute q/k/v (m = wave-1)
    if(wave>=1 && lane<kD){
      int m=wave-1;
      float a=c_qkvb+dot48d((const __half2*)xvH[chain], Wl + m*2688 + lane*56);
      int hh=lane/kHD, dd=lane%kHD;
      if(m==0) qS[chain][hh*16+dd]=a;
      else if(m==1) Kh[chain][(hh*kT+t)*kHD+dd]=a;
      else          Vh[chain][(hh*kT+t)*kHD+dd]=a;
    }
    __syncthreads();                                   // B1
    // stage2: self-attn (fp32), head = wave, lane = key
    {
      float p=0.f, pv[kHD];
      #pragma unroll
      for(int u=0;u<kHD;u++) pv[u]=0.f;
      if(lane<=t){
        float s=dot12f((const float4*)(qS[chain]+wave*16),
                       (const float4*)(Kh[chain]+(wave*kT+lane)*kHD))*rs;
        p=__expf(s);
        const float4* vp=(const float4*)(Vh[chain]+(wave*kT+lane)*kHD);
        float4 v0=vp[0], v1=vp[1], v2=vp[2];
        float vr[kHD]={v0.x,v0.y,v0.z,v0.w,v1.x,v1.y,v1.z,v1.w,v2.x,v2.y,v2.z,v2.w};
        #pragma unroll
        for(int u=0;u<kHD;u++) pv[u]=p*vr[u];
      }
      float l=wsum(p);
      #pragma unroll
      for(int u=0;u<kHD;u++) pv[u]=wsum(pv[u]);
      if(lane==0){
        float inv=1.f/l;
        #pragma unroll
        for(int u=0;u<6;u++)
          ((__half2*)soH[chain])[wave*6+u]=__floats2half2_rn(pv[2*u]*inv, pv[2*u+1]*inv);
      }
    }
    __syncthreads();                                   // B2
    // stage3: wave0 — self o-proj + residual + LN1 + cross-q
    if(wave==0){
      float rr=0.f;
      if(lane<kD)
        rr=xv+c_bo+dot48d((const __half2*)soH[chain], Wl+8064+lane*56);
      float s1=wsum(rr), s2=wsum(rr*rr);
      float mean=s1*(1.f/48.f);
      float rstd=rsqrtf(s2*(1.f/48.f)-mean*mean+1e-5f);
      h1=0;
      if(lane<kD){ h1=(rr-mean)*rstd*g1+bb1; h1H[chain][lane]=__float2half(h1); }
      wsync();
      if(lane<kD)
        cqH[chain][lane]=__float2half(c_cbq+dot48d((const __half2*)h1H[chain], Wl+10752+lane*56));
    }
    __syncthreads();                                   // B3
    // stage4: cross-attn from registers, head = wave; max-sub for fp16 P
    {
      __half2 q2[6];
      #pragma unroll
      for(int c=0;c<6;c++) q2[c]=((const __half2*)cqH[chain])[wave*6+c];
      float s[8];
      #pragma unroll
      for(int i=0;i<4;i++){
        #pragma unroll
        for(int e=0;e<2;e++){
          float a0=0.f,a1=0.f;
          const __half2* kp=Kr2[i][e];
          a0=fdot2(q2[0],kp[0],a0); a1=fdot2(q2[1],kp[1],a1);
          a0=fdot2(q2[2],kp[2],a0); a1=fdot2(q2[3],kp[3],a1);
          a0=fdot2(q2[4],kp[4],a0); a1=fdot2(q2[5],kp[5],a1);
          s[2*i+e]=(a0+a1)*rs;
        }
      }
      float mloc=s[0];
      #pragma unroll
      for(int j=1;j<8;j++) mloc=fmaxf(mloc,s[j]);
      float M=wmax(mloc);
      float p[8], l=0.f;
      #pragma unroll
      for(int j=0;j<8;j++){ p[j]=__expf(s[j]-M); l+=p[j]; }
      l=wsum(l);
      float inv=1.f/l;
      __half2 ph[4];
      #pragma unroll
      for(int i=0;i<4;i++) ph[i]=__floats2half2_rn(p[2*i],p[2*i+1]);
      float acc[kHD];
      #pragma unroll
      for(int u=0;u<kHD;u++) acc[u]=0.f;
      #pragma unroll
      for(int i=0;i<4;i++){
        #pragma unroll
        for(int u=0;u<kHD;u++) acc[u]=fdot2(ph[i],Vr2[i][u],acc[u]);
      }
      #pragma unroll
      for(int u=0;u<kHD;u++) acc[u]=wsum(acc[u]);
      if(lane==0){
        #pragma unroll
        for(int u=0;u<6;u++)
          ((__half2*)covH[chain])[wave*6+u]=__floats2half2_rn(acc[2*u]*inv, acc[2*u+1]*inv);
      }
    }
    __syncthreads();                                   // B4
    // stage5: wave0 — cross o-proj + residual + LN2
    if(wave==0){
      float rr=0.f;
      if(lane<kD)
        rr=h1+c_cbo+dot48d((const __half2*)covH[chain], Wl+13440+lane*56);
      float s1=wsum(rr), s2=wsum(rr*rr);
      float mean=s1*(1.f/48.f);
      float rstd=rsqrtf(s2*(1.f/48.f)-mean*mean+1e-5f);
      h2=0;
      if(lane<kD){ h2=(rr-mean)*rstd*g2+bb2; h2H[chain][lane]=__float2half(h2); }
    }
    __syncthreads();                                   // B5
    // stage6: FFN1 on waves 0,1 (col = wave*64 + lane)
    if(wave<2){
      int col=wave*64+lane;
      float a=c_fb1+dot48d((const __half2*)h2H[chain], Wl+16128+col*56);
      f1H[chain][col]=__float2half(fmaxf(a,0.f));
    }
    __syncthreads();                                   // B6
    // stage7: wave0 — FFN2 + residual + LN3 + output
    if(wave==0){
      float rr=0.f;
      if(lane<kD)
        rr=h2+c_fb2+dot128d((const __half2*)f1H[chain], Wl+23296+lane*136);
      float s1=wsum(rr), s2=wsum(rr*rr);
      float mean=s1*(1.f/48.f);
      float rstd=rsqrtf(s2*(1.f/48.f)-mean*mean+1e-5f);
      float cv=0.f;
      if(lane<kD){ cv=(rr-mean)*rstd*g3+bb3; cur=cv; }
      float y=wsum(cv*c_ow);
      if(lane==0) out[b*kT+t]=y+c_ob;
    }
  }
}

extern "C" void kernel_launch(void* const* d_in, const int* in_sizes, int n_in,
                              void* d_out, int out_size, void* d_ws, size_t ws_size,
                              hipStream_t stream){
  // ws: Wh fp16 (reserve 65536 B), A fp32 NB, H1/H2/H3 fp16 NB each (~31.5 MiB).
  float* ws = (float*)d_ws;
  __half* Wh = (__half*)ws;
  const size_t NB = (size_t)kB*kS*kD;     // 3,145,728
  float*  A  = ws + 16384;
  __half* H1 = (__half*)(A + NB);
  __half* H2 = H1 + NB;
  __half* H3 = H2 + NB;

  k_embed<<<(kB*kS*kD+255)/256,256,0,stream>>>((const float*)d_in[0],(const float*)d_in[1],(const float*)d_in[2],A);
  k_qkv  <<<(kB*kS)/32,256,0,stream>>>(A,(const float*)d_in[4],(const float*)d_in[5],(const float*)d_in[6],
                                       (const float*)d_in[7],(const float*)d_in[8],(const float*)d_in[9],H1,H2,H3);
  k_attn <<<kB*kNH,256,0,stream>>>(H1,H2,H3,H1);
  k_oproj_ln<<<(kB*kS)/32,256,0,stream>>>(A,H1,(const float*)d_in[10],(const float*)d_in[11],
                                          (const float*)d_in[12],(const float*)d_in[13],H2);
  k_ffn_ln  <<<(kB*kS)/16,256,0,stream>>>(H2,(const float*)d_in[14],(const float*)d_in[15],(const float*)d_in[16],
                                          (const float*)d_in[17],(const float*)d_in[18],(const float*)d_in[19],A);
  k_ckv     <<<(kB*kS)/32,256,0,stream>>>(A,(const float*)d_in[32],(const float*)d_in[33],
                                          (const float*)d_in[34],(const float*)d_in[35],H1,H3);
  k_prep    <<<(26112+255)/256,256,0,stream>>>((const float*)d_in[20],(const float*)d_in[22],(const float*)d_in[24],
                                               (const float*)d_in[26],(const float*)d_in[30],(const float*)d_in[36],
                                               (const float*)d_in[40],(const float*)d_in[42],Wh);
  DecP P;
  P.dec_start=(const float*)d_in[3];
  P.sbq=(const float*)d_in[21]; P.sbk=(const float*)d_in[23]; P.sbv=(const float*)d_in[25]; P.sbo=(const float*)d_in[27];
  P.ln1g=(const float*)d_in[28]; P.ln1b=(const float*)d_in[29];
  P.cbq=(const float*)d_in[31]; P.cbo=(const float*)d_in[37];
  P.ln2g=(const float*)d_in[38]; P.ln2b=(const float*)d_in[39];
  P.fb1=(const float*)d_in[41]; P.fb2=(const float*)d_in[43];
  P.ln3g=(const float*)d_in[44]; P.ln3b=(const float*)d_in[45];
  P.ow=(const float*)d_in[46]; P.ob=(const float*)d_in[47];
  k_dec<<<kB/2,512,0,stream>>>(H1,H3,Wh,P,(float*)d_out);
}

// Round 4
// 589.303 us; speedup vs baseline: 1.5444x; 1.1398x over previous
//
#include <hip/hip_runtime.h>
#include <hip/hip_bf16.h>
#include <hip/hip_fp16.h>

// Inputs/outputs are FP32 (verified R3/R6).
// R10 lesson: KV-in-regs OR weights-in-regs — never both (VGPR cap 256 -> spill).
// R11 lesson: redundant all-wave broadcast stages LOSE (4x LDS traffic > 3 barriers).
// R12 lesson: v_dot2 + fp16 LDS cut k_dec 450->335; VALUBusy 8% -> latency-bound.
// R13 lesson: dual-chain/block doubles per-CU throughput but wall time is set by
//   per-step CRITICAL PATH (blocks already concurrent at 128 <= 256 CUs). ~12k cy/step
//   vs ~3.5k modeled -> overhead is in barriers + cross-wave LDS handoffs.
// R14: collapse to 2 barriers/step. Everything except cross-attn runs on wave0
//   with intra-wave wsync only (DS ops in-order within a wave). Self-attn done
//   4-heads-in-one-wave via 16-lane DPP row reductions. Single chain per block.

constexpr int kB  = 128;
constexpr int kS  = 512;
constexpr int kT  = 64;
constexpr int kD  = 48;
constexpr int kFF = 128;
constexpr int kNH = 4;
constexpr int kHD = 12;

__device__ __forceinline__ void wsync(){
  __builtin_amdgcn_wave_barrier();
  asm volatile("" ::: "memory");
}

// ---- DPP wave64 reductions (VALU-speed) ----
template<int CTRL,int RM,int BM,bool BC>
__device__ __forceinline__ float dppmov(float x, float old){
  return __builtin_bit_cast(float, __builtin_amdgcn_update_dpp(
      __builtin_bit_cast(int, old), __builtin_bit_cast(int, x), CTRL, RM, BM, BC));
}
// sum across 64 lanes, result uniform in all lanes
__device__ __forceinline__ float wsum(float x){
  x += dppmov<0x111,0xf,0xf,true>(x, 0.f);   // row_shr:1
  x += dppmov<0x112,0xf,0xf,true>(x, 0.f);   // row_shr:2
  x += dppmov<0x114,0xf,0xf,true>(x, 0.f);   // row_shr:4
  x += dppmov<0x118,0xf,0xf,true>(x, 0.f);   // row_shr:8
  x += dppmov<0x142,0xa,0xf,true>(x, 0.f);   // row_bcast:15 -> rows 1,3
  x += dppmov<0x143,0xc,0xf,true>(x, 0.f);   // row_bcast:31 -> rows 2,3
  return __builtin_bit_cast(float, __builtin_amdgcn_readlane(__builtin_bit_cast(int, x), 63));
}
__device__ __forceinline__ float wmax(float x){
  const float NI = -3.4e38f;
  x = fmaxf(x, dppmov<0x111,0xf,0xf,false>(x, NI));
  x = fmaxf(x, dppmov<0x112,0xf,0xf,false>(x, NI));
  x = fmaxf(x, dppmov<0x114,0xf,0xf,false>(x, NI));
  x = fmaxf(x, dppmov<0x118,0xf,0xf,false>(x, NI));
  x = fmaxf(x, dppmov<0x142,0xa,0xf,false>(x, NI));
  x = fmaxf(x, dppmov<0x143,0xc,0xf,false>(x, NI));
  return __builtin_bit_cast(float, __builtin_amdgcn_readlane(__builtin_bit_cast(int, x), 63));
}
// sum within each 16-lane row; result valid at lane 15 of each row
__device__ __forceinline__ float rowsum16(float x){
  x += dppmov<0x111,0xf,0xf,true>(x, 0.f);
  x += dppmov<0x112,0xf,0xf,true>(x, 0.f);
  x += dppmov<0x114,0xf,0xf,true>(x, 0.f);
  x += dppmov<0x118,0xf,0xf,true>(x, 0.f);
  return x;
}

// pe[p, 2i] = sin(p * exp(-2i*ln(10000)/48)), pe[p, 2i+1] = cos(...)
__device__ __forceinline__ float pe_val(int p, int j){   // precise (table init)
  int i = j >> 1;
  float f = expf(-0.19188209108283716f * (float)(2*i));
  float a = (float)p * f;
  return (j & 1) ? cosf(a) : sinf(a);
}
__device__ __forceinline__ float pe_fast(int p, int j){  // encoder embed
  int i = j >> 1;
  float f = __expf(-0.19188209108283716f * (float)(2*i));
  float a = (float)p * f;
  return (j & 1) ? __cosf(a) : __sinf(a);
}

// ---- packed fp16 dot: d = a.x*b.x + a.y*b.y + c (v_dot2_f32_f16) ----
typedef _Float16 h2v __attribute__((ext_vector_type(2)));
union H2U { __half2 h; h2v v; };
__device__ __forceinline__ float fdot2(__half2 a, __half2 b, float c){
#if __has_builtin(__builtin_amdgcn_fdot2)
  H2U ua, ub; ua.h=a; ub.h=b;
  return __builtin_amdgcn_fdot2(ua.v, ub.v, c, false);
#else
  float2 fa=__half22float2(a), fb=__half22float2(b);
  return fmaf(fa.y, fb.y, fmaf(fa.x, fb.x, c));
#endif
}

// 48-dot, both operands fp16 (LDS or regs), 4 accumulator chains
__device__ __forceinline__ float dot48d(const __half2* x, const __half* w){
  const __half2* w2=(const __half2*)w;
  float a0=0.f,a1=0.f,a2=0.f,a3=0.f;
  #pragma unroll
  for(int c=0;c<6;c++){
    a0=fdot2(x[4*c+0],w2[4*c+0],a0);
    a1=fdot2(x[4*c+1],w2[4*c+1],a1);
    a2=fdot2(x[4*c+2],w2[4*c+2],a2);
    a3=fdot2(x[4*c+3],w2[4*c+3],a3);
  }
  return (a0+a1)+(a2+a3);
}
// 128-dot, 8 accumulator chains
__device__ __forceinline__ float dot128d(const __half2* x, const __half* w){
  const __half2* w2=(const __half2*)w;
  float a0=0.f,a1=0.f,a2=0.f,a3=0.f,a4=0.f,a5=0.f,a6=0.f,a7=0.f;
  #pragma unroll
  for(int c=0;c<8;c++){
    a0=fdot2(x[8*c+0],w2[8*c+0],a0);
    a1=fdot2(x[8*c+1],w2[8*c+1],a1);
    a2=fdot2(x[8*c+2],w2[8*c+2],a2);
    a3=fdot2(x[8*c+3],w2[8*c+3],a3);
    a4=fdot2(x[8*c+4],w2[8*c+4],a4);
    a5=fdot2(x[8*c+5],w2[8*c+5],a5);
    a6=fdot2(x[8*c+6],w2[8*c+6],a6);
    a7=fdot2(x[8*c+7],w2[8*c+7],a7);
  }
  return ((a0+a1)+(a2+a3))+((a4+a5)+(a6+a7));
}

// ---------------- K1: embed + PE -> X0 (fp32) ----------------
__global__ void k_embed(const float* __restrict__ src, const float* __restrict__ in_w,
                        const float* __restrict__ in_b, float* __restrict__ X0){
  int idx = blockIdx.x*256 + threadIdx.x;
  if (idx >= kB*kS*kD) return;
  int j = idx % kD; int bs = idx / kD; int s = bs % kS;
  float v = (src[bs] * in_w[j] + in_b[j]) * 6.928203230275509f;
  X0[idx] = v + pe_fast(s, j);
}

// ---------------- K2: encoder QKV projection, fp16 x + dot2 ----------------
__global__ void __launch_bounds__(256) k_qkv(const float* __restrict__ X,
    const float* __restrict__ wq, const float* __restrict__ bq,
    const float* __restrict__ wk, const float* __restrict__ bk,
    const float* __restrict__ wv, const float* __restrict__ bv,
    __half* __restrict__ Q, __half* __restrict__ K, __half* __restrict__ V){
  __shared__ __align__(16) __half W[3*2688];     // col stride 56 halves
  __shared__ __align__(16) float bias[3*kD];
  __shared__ __align__(16) __half2 xt2[32*24];
  int tid = threadIdx.x;
  for (int i=tid;i<3*2304;i+=256){ int m=i/2304, e=i%2304, k=e/48, j=e%48;
    const float* w = (m==0)?wq:((m==1)?wk:wv);
    W[m*2688 + j*56 + k] = __float2half(w[e]); }
  for (int i=tid;i<3*kD;i+=256){ int m=i/kD,e=i%kD;
    const float* w=(m==0)?bq:((m==1)?bk:bv); bias[i]=w[e]; }
  long row0 = (long)blockIdx.x*32;
  const float2* Xp=(const float2*)(X+row0*kD);
  for (int i=tid;i<768;i+=256){ float2 v=Xp[i]; xt2[i]=__floats2half2_rn(v.x,v.y); }
  __syncthreads();
  int r = tid>>3, c0 = tid&7;
  __half2 xr[24];
  #pragma unroll
  for(int u=0;u<24;u++) xr[u]=xt2[r*24+u];
  for (int c=c0; c<3*kD; c+=8){
    int m=c/kD, j=c%kD;
    float acc = bias[m*kD+j] + dot48d(xr, W + m*2688 + j*56);
    __half* o = (m==0)?Q:((m==1)?K:V);
    o[(row0+r)*kD+j]=__float2half(acc);
  }
}

// ---------------- K3: encoder attention — half2 K (dot2 scores), fp32 V/P ----------------
__global__ void __launch_bounds__(256) k_attn(const __half* Q, const __half* __restrict__ K,
                       const __half* __restrict__ V, __half* O){
  int b = blockIdx.x / kNH, h = blockIdx.x % kNH;
  __shared__ __align__(16) __half2 Ks2[kS*6];  // 12 KB
  __shared__ __align__(16) float   Vs[kS*kHD]; // 24 KB (fp32: P stays fp32, no overflow)
  int tid = threadIdx.x;
  long base = ((long)b*kS)*kD + h*kHD;
  for (int i=tid;i<kS*6;i+=256){ int r=i/6, c=i%6;
    Ks2[i]=*(const __half2*)&K[base+(long)r*kD+2*c]; }
  for (int i=tid;i<kS*kHD;i+=256){ int r=i/kHD, d=i%kHD;
    Vs[i]=__half2float(V[base+(long)r*kD+d]); }
  const float rs = 0.28867513459481287f;
  int q0 = tid, q1 = tid+256;
  __half2 qa2[6], qb2[6];
  {
    const __half2* qp0=(const __half2*)(Q+base+(long)q0*kD);
    const __half2* qp1=(const __half2*)(Q+base+(long)q1*kD);
    #pragma unroll
    for(int c=0;c<6;c++){ qa2[c]=qp0[c]; qb2[c]=qp1[c]; }
  }
  __syncthreads();
  float acc0[kHD], acc1[kHD];
  #pragma unroll
  for(int j=0;j<kHD;j++){ acc0[j]=0.f; acc1[j]=0.f; }
  float l0=0.f, l1=0.f;
  for(int k=0;k<kS;k++){
    const __half2* kp=Ks2+k*6;
    float sA0=0.f,sA1=0.f,sB0=0.f,sB1=0.f;
    #pragma unroll
    for(int c=0;c<3;c++){
      sA0=fdot2(qa2[2*c],kp[2*c],sA0); sA1=fdot2(qa2[2*c+1],kp[2*c+1],sA1);
      sB0=fdot2(qb2[2*c],kp[2*c],sB0); sB1=fdot2(qb2[2*c+1],kp[2*c+1],sB1);
    }
    float p0=__expf((sA0+sA1)*rs), p1=__expf((sB0+sB1)*rs);
    l0+=p0; l1+=p1;
    const float4* vp=(const float4*)(Vs+k*kHD);
    float4 va=vp[0], vb4=vp[1], vc4=vp[2];
    float vr[kHD]={va.x,va.y,va.z,va.w,vb4.x,vb4.y,vb4.z,vb4.w,vc4.x,vc4.y,vc4.z,vc4.w};
    #pragma unroll
    for(int j=0;j<kHD;j++){ acc0[j]+=p0*vr[j]; acc1[j]+=p1*vr[j]; }
  }
  float i0=1.f/l0, i1=1.f/l1;
  #pragma unroll
  for(int j=0;j<kHD;j++){
    O[base+(long)q0*kD+j]=__float2half(acc0[j]*i0);
    O[base+(long)q1*kD+j]=__float2half(acc1[j]*i1);
  }
}

// ---------------- K4: o-proj + residual + LN, dot2 ----------------
__global__ void __launch_bounds__(256) k_oproj_ln(const float* __restrict__ Xres, const __half* __restrict__ O,
      const float* __restrict__ wo, const float* __restrict__ bo,
      const float* __restrict__ g, const float* __restrict__ bb,
      __half* __restrict__ Xout){
  __shared__ __align__(16) __half W[kD*56];
  __shared__ float bsh[kD], gs[kD], bs2[kD];
  __shared__ __align__(16) float res[32*kD];
  __shared__ __align__(16) __half2 ot2[32*24];
  __shared__ float mrow[32], rstd[32];
  int tid=threadIdx.x;
  for(int i=tid;i<kD*kD;i+=256){ int k=i/48, j=i%48; W[j*56+k]=__float2half(wo[i]); }
  if(tid<kD){ bsh[tid]=bo[tid]; gs[tid]=g[tid]; bs2[tid]=bb[tid]; }
  long row0=(long)blockIdx.x*32;
  const __half2* Op=(const __half2*)(O+row0*kD);
  for(int i=tid;i<768;i+=256) ot2[i]=Op[i];
  __syncthreads();
  int r=tid>>3, c0=tid&7;
  __half2 orow[24];
  #pragma unroll
  for(int u=0;u<24;u++) orow[u]=ot2[r*24+u];
  for(int j=c0;j<kD;j+=8){
    float acc=bsh[j]+dot48d(orow, W+j*56);
    res[r*kD+j]=Xres[row0*kD + r*kD + j]+acc;
  }
  __syncthreads();
  if(tid<32){
    float s=0.f, s2=0.f;
    for(int j=0;j<kD;j++){ float v=res[tid*kD+j]; s+=v; s2+=v*v; }
    float m=s*(1.f/kD);
    mrow[tid]=m; rstd[tid]=rsqrtf(s2*(1.f/kD)-m*m+1e-5f);
  }
  __syncthreads();
  for(int i=tid;i<32*kD;i+=256){int r2=i/kD,j=i%kD;
    Xout[row0*kD+i]=__float2half((res[i]-mrow[r2])*rstd[r2]*gs[j]+bs2[j]); }
}

// ---------------- K5: FFN + residual + LN, dot2 ----------------
__global__ void __launch_bounds__(256) k_ffn_ln(const __half* __restrict__ Xin,
   const float* __restrict__ w1, const float* __restrict__ b1,
   const float* __restrict__ w2, const float* __restrict__ b2,
   const float* __restrict__ g, const float* __restrict__ bb,
   float* __restrict__ Xout){
  __shared__ __align__(16) __half W1[kFF*56];
  __shared__ __align__(16) __half W2[kD*136];
  __shared__ float b1s[kFF], b2s[kD], gs[kD], bs2[kD];
  __shared__ __align__(16) __half xt[16*kD];
  __shared__ __align__(16) __half h1h[16*kFF];
  __shared__ __align__(16) float res[16*kD];
  __shared__ float mrow[16], rstd[16];
  int tid=threadIdx.x;
  for(int i=tid;i<kD*kFF;i+=256){ int k=i/128, c=i%128; W1[c*56+k]=__float2half(w1[i]); }
  for(int i=tid;i<kFF*kD;i+=256){ int u=i/48, j=i%48; W2[j*136+u]=__float2half(w2[i]); }
  if(tid<kFF) b1s[tid]=b1[tid];
  if(tid<kD){ b2s[tid]=b2[tid]; gs[tid]=g[tid]; bs2[tid]=bb[tid]; }
  long row0=(long)blockIdx.x*16;
  const __half2* Xp=(const __half2*)(Xin+row0*kD);
  for(int i=tid;i<384;i+=256) ((__half2*)xt)[i]=Xp[i];
  __syncthreads();
  int r=tid>>4, c0=tid&15;
  {
    __half2 xr[24];
    const __half2* xp=(const __half2*)(xt + r*kD);
    #pragma unroll
    for(int u=0;u<24;u++) xr[u]=xp[u];
    for(int c=c0;c<kFF;c+=16){
      float acc=b1s[c]+dot48d(xr, W1+c*56);
      h1h[r*kFF+c]=__float2half(fmaxf(acc,0.f));
    }
  }
  __syncthreads();
  {
    const __half2* hp=(const __half2*)(h1h + r*kFF);
    for(int j=c0;j<kD;j+=16){
      float acc=b2s[j]+dot128d(hp, W2+j*136);
      res[r*kD+j]=__half2float(xt[r*kD+j])+acc;
    }
  }
  __syncthreads();
  if(tid<16){
    float s=0.f, s2=0.f;
    for(int j=0;j<kD;j++){ float v=res[tid*kD+j]; s+=v; s2+=v*v; }
    float m=s*(1.f/kD);
    mrow[tid]=m; rstd[tid]=rsqrtf(s2*(1.f/kD)-m*m+1e-5f);
  }
  __syncthreads();
  for(int i=tid;i<16*kD;i+=256){int r2=i/kD,j=i%kD;
    Xout[row0*kD+i]=(res[i]-mrow[r2])*rstd[r2]*gs[j]+bs2[j]; }
}

// ---------------- K6: cross K/V projection — K row-major [b][s][d], V transposed [b][d][s] ----------------
__global__ void __launch_bounds__(256) k_ckv(const float* __restrict__ M,
    const float* __restrict__ wk, const float* __restrict__ bk,
    const float* __restrict__ wv, const float* __restrict__ bv,
    __half* __restrict__ Kc, __half* __restrict__ Vc){
  __shared__ __align__(16) __half W[2*2688];
  __shared__ float bias[2*kD];
  __shared__ __align__(16) __half2 xt2[32*24];
  int tid=threadIdx.x;
  for(int i=tid;i<2*2304;i+=256){ int m=i/2304, e=i%2304, k=e/48, j=e%48;
    W[m*2688 + j*56 + k] = __float2half((m?wv:wk)[e]); }
  for(int i=tid;i<2*kD;i+=256){ int m=i/kD,e=i%kD; bias[i]=(m?bv:bk)[e]; }
  long row0=(long)blockIdx.x*32;
  const float2* Mp=(const float2*)(M+row0*kD);
  for(int i=tid;i<768;i+=256){ float2 v=Mp[i]; xt2[i]=__floats2half2_rn(v.x,v.y); }
  __syncthreads();
  int r=tid>>3, c0=tid&7;
  __half2 xr[24];
  #pragma unroll
  for(int u=0;u<24;u++) xr[u]=xt2[r*24+u];
  long gr=row0+r; long bb2=gr>>9; long s=gr&511;
  for(int c=c0;c<2*kD;c+=8){
    int m=c/kD, j=c%kD;
    float acc=bias[m*kD+j]+dot48d(xr, W+m*2688+j*56);
    if(m==0) Kc[(bb2*kS+s)*kD + j]=__float2half(acc);     // [b][s][d]
    else     Vc[(bb2*kD+j)*kS + s]=__float2half(acc);     // [b][d][s]
  }
}

// ---------------- K0: decoder weights -> padded FP16, column-major ----------------
// Wh halves: 6 mats 48 cols stride 56: swq@0 swk@2688 swv@5376 swo@8064 cwq@10752
// cwo@13440; w1 128 cols stride 56 @16128; w2 48 cols stride 136 @23296. Tot 29824.
__global__ void k_prep(const float* __restrict__ swq,const float* __restrict__ swk,
                       const float* __restrict__ swv,const float* __restrict__ swo,
                       const float* __restrict__ cwq,const float* __restrict__ cwo,
                       const float* __restrict__ w1,const float* __restrict__ w2,
                       __half* __restrict__ Wh){
  int idx=blockIdx.x*256+threadIdx.x;
  if(idx>=26112) return;
  if(idx<13824){
    int m=idx/2304, e=idx%2304, j=e/48, k=e%48;
    const float* w = (m==0)?swq:((m==1)?swk:((m==2)?swv:((m==3)?swo:((m==4)?cwq:cwo))));
    Wh[m*2688 + j*56 + k] = __float2half(w[k*48+j]);
  } else if(idx<19968){
    int e=idx-13824, c=e/48, k=e%48;
    Wh[16128 + c*56 + k] = __float2half(w1[k*128+c]);
  } else {
    int e=idx-19968, j=e/128, u=e%128;
    Wh[23296 + j*136 + u] = __float2half(w2[u*48+j]);
  }
}

// ---------------- K7: decoder — R14: 2 barriers/step, mega-wave0 segment ----------------
struct DecP {
  const float *dec_start, *sbq, *sbk, *sbv, *sbo, *ln1g, *ln1b,
              *cbq, *cbo, *ln2g, *ln2b, *fb1, *fb2, *ln3g, *ln3b, *ow, *ob;
};

__global__ void __launch_bounds__(256,1) k_dec(const __half* __restrict__ KT,
    const __half* __restrict__ VT, const __half* __restrict__ Wg, DecP P,
    float* __restrict__ out){
  __shared__ __align__(16) __half Wl[29824];       // fp16 weights, 58.25 KB
  __shared__ __align__(16) float peT[kT*kD];       // PE table, 12 KB
  __shared__ __align__(16) __half KhH[kNH*kT*kHD]; // self-K cache fp16, 6 KB
  __shared__ __align__(16) float  Vh[kNH*kT*kHD];  // self-V cache fp32, 12 KB
  __shared__ __align__(16) __half qSH[kNH*kHD];    // q by head, fp16
  __shared__ __align__(16) __half xvH[kD], soH[kD], h1H[kD], cqH[kD], covH[kD], h2H[kD];
  __shared__ __align__(16) __half f1H[kFF];
  int tid=threadIdx.x, b=blockIdx.x, wave=tid>>6, lane=tid&63;
  const float rs=0.28867513459481287f;

  for(int i=tid;i<29824/8;i+=256) ((float4*)Wl)[i]=((const float4*)Wg)[i];
  for(int i=tid;i<kT*kD;i+=256){ int tt=i/kD, j=i%kD; peT[i]=pe_val(tt,j); }

  // wave0 per-lane constants (wave0 runs every stage except cross-attn)
  float cur=0, c_sbq=0,c_sbk=0,c_sbv=0, c_bo=0,c_cbq=0,c_cbo=0,c_fb2=0;
  float g1=0,bb1=0,g2=0,bb2=0,g3=0,bb3=0,c_ow=0, c_fb1a=0,c_fb1b=0;
  if(wave==0){
    if(lane<kD){
      cur=P.dec_start[lane];
      c_sbq=P.sbq[lane]; c_sbk=P.sbk[lane]; c_sbv=P.sbv[lane];
      c_bo=P.sbo[lane]; c_cbq=P.cbq[lane]; c_cbo=P.cbo[lane]; c_fb2=P.fb2[lane];
      g1=P.ln1g[lane]; bb1=P.ln1b[lane];
      g2=P.ln2g[lane]; bb2=P.ln2b[lane];
      g3=P.ln3g[lane]; bb3=P.ln3b[lane];
      c_ow=P.ow[lane];
    }
    c_fb1a=P.fb1[lane]; c_fb1b=P.fb1[lane+64];
  }
  float c_ob=P.ob[0];

  // cross-attn K/V resident in registers: head = wave, 4 key-PAIRS per lane
  // Kc layout [b][s][d]; Vc layout [b][d][s] read as half2 pairs along s.
  __half2 Kr2[4][2][6], Vr2[4][kHD];   // 48 + 48 VGPRs
  {
    const __half* Kb = KT + (long)b*kS*kD;
    const __half2* Vb = (const __half2*)VT + (long)b*kD*(kS/2);
    #pragma unroll
    for(int i=0;i<4;i++){
      int sp = lane + 64*i;
      #pragma unroll
      for(int e=0;e<2;e++){
        const __half2* kp=(const __half2*)(Kb + (long)(2*sp+e)*kD + wave*kHD);
        #pragma unroll
        for(int c=0;c<6;c++) Kr2[i][e][c]=kp[c];
      }
      #pragma unroll
      for(int u=0;u<kHD;u++) Vr2[i][u]=Vb[(wave*kHD+u)*(kS/2)+sp];
    }
  }
  __syncthreads();

  float h1=0, h2=0, xv=0;
  for(int t=0;t<kT;t++){
    // ======== A: wave0-only segment (wsync handoffs, no block barriers) ========
    if(wave==0){
      // A0: x = cur + pe
      if(lane<kD){ xv=cur+peT[t*kD+lane]; xvH[lane]=__float2half(xv); }
      wsync();
      // A1: qkv — 3 independent dots per lane (pipelined)
      if(lane<kD){
        float qv=c_sbq+dot48d((const __half2*)xvH, Wl + 0*2688 + lane*56);
        float kv=c_sbk+dot48d((const __half2*)xvH, Wl + 1*2688 + lane*56);
        float vv=c_sbv+dot48d((const __half2*)xvH, Wl + 2*2688 + lane*56);
        int hh=lane/kHD, dd=lane%kHD;
        qSH[lane]=__float2half(qv);
        KhH[(hh*kT+t)*kHD+dd]=__float2half(kv);
        Vh[(hh*kT+t)*kHD+dd]=vv;
      }
      wsync();
      // A2: self-attn, 4 heads in one wave: lane = head*16 + keygroup
      {
        int hh=lane>>4, g=lane&15;
        __half2 q2[6];
        const __half2* qp=(const __half2*)qSH + hh*6;
        #pragma unroll
        for(int c=0;c<6;c++) q2[c]=qp[c];
        float l=0.f, acc[kHD];
        #pragma unroll
        for(int u=0;u<kHD;u++) acc[u]=0.f;
        #pragma unroll
        for(int kk=0;kk<4;kk++){
          int key=g+16*kk;
          if(key<=t){
            const __half2* kp=(const __half2*)KhH + (hh*kT+key)*6;
            float a0=0.f,a1=0.f;
            a0=fdot2(q2[0],kp[0],a0); a1=fdot2(q2[1],kp[1],a1);
            a0=fdot2(q2[2],kp[2],a0); a1=fdot2(q2[3],kp[3],a1);
            a0=fdot2(q2[4],kp[4],a0); a1=fdot2(q2[5],kp[5],a1);
            float p=__expf((a0+a1)*rs);
            l+=p;
            const float4* vp=(const float4*)(Vh+(hh*kT+key)*kHD);
            float4 v0=vp[0], v1=vp[1], v2=vp[2];
            float vr[kHD]={v0.x,v0.y,v0.z,v0.w,v1.x,v1.y,v1.z,v1.w,v2.x,v2.y,v2.z,v2.w};
            #pragma unroll
            for(int u=0;u<kHD;u++) acc[u]+=p*vr[u];
          }
        }
        l=rowsum16(l);
        #pragma unroll
        for(int u=0;u<kHD;u++) acc[u]=rowsum16(acc[u]);
        if(g==15){
          float inv=1.f/l;
          #pragma unroll
          for(int u=0;u<6;u++)
            ((__half2*)soH)[hh*6+u]=__floats2half2_rn(acc[2*u]*inv, acc[2*u+1]*inv);
        }
      }
      wsync();
      // A3: self o-proj + residual + LN1
      {
        float rr=0.f;
        if(lane<kD)
          rr=xv+c_bo+dot48d((const __half2*)soH, Wl+8064+lane*56);
        float s1=wsum(rr), s2=wsum(rr*rr);
        float mean=s1*(1.f/48.f);
        float rstd=rsqrtf(s2*(1.f/48.f)-mean*mean+1e-5f);
        h1=0;
        if(lane<kD){ h1=(rr-mean)*rstd*g1+bb1; h1H[lane]=__float2half(h1); }
      }
      wsync();
      // A4: cross-q
      if(lane<kD)
        cqH[lane]=__float2half(c_cbq+dot48d((const __half2*)h1H, Wl+10752+lane*56));
    }
    __syncthreads();                                   // B1: cqH -> all waves
    // ======== X: cross-attn on all 4 waves (head = wave) ========
    {
      __half2 q2[6];
      #pragma unroll
      for(int c=0;c<6;c++) q2[c]=((const __half2*)cqH)[wave*6+c];
      float s[8];
      #pragma unroll
      for(int i=0;i<4;i++){
        #pragma unroll
        for(int e=0;e<2;e++){
          float a0=0.f,a1=0.f;
          const __half2* kp=Kr2[i][e];
          a0=fdot2(q2[0],kp[0],a0); a1=fdot2(q2[1],kp[1],a1);
          a0=fdot2(q2[2],kp[2],a0); a1=fdot2(q2[3],kp[3],a1);
          a0=fdot2(q2[4],kp[4],a0); a1=fdot2(q2[5],kp[5],a1);
          s[2*i+e]=(a0+a1)*rs;
        }
      }
      float mloc=s[0];
      #pragma unroll
      for(int j=1;j<8;j++) mloc=fmaxf(mloc,s[j]);
      float M=wmax(mloc);
      float p[8], l=0.f;
      #pragma unroll
      for(int j=0;j<8;j++){ p[j]=__expf(s[j]-M); l+=p[j]; }
      l=wsum(l);
      float inv=1.f/l;
      __half2 ph[4];
      #pragma unroll
      for(int i=0;i<4;i++) ph[i]=__floats2half2_rn(p[2*i],p[2*i+1]);
      float acc[kHD];
      #pragma unroll
      for(int u=0;u<kHD;u++) acc[u]=0.f;
      #pragma unroll
      for(int i=0;i<4;i++){
        #pragma unroll
        for(int u=0;u<kHD;u++) acc[u]=fdot2(ph[i],Vr2[i][u],acc[u]);
      }
      #pragma unroll
      for(int u=0;u<kHD;u++) acc[u]=wsum(acc[u]);
      if(lane==0){
        #pragma unroll
        for(int u=0;u<6;u++)
          ((__half2*)covH)[wave*6+u]=__floats2half2_rn(acc[2*u]*inv, acc[2*u+1]*inv);
      }
    }
    __syncthreads();                                   // B2: covH -> wave0
    // ======== C: wave0-only segment ========
    if(wave==0){
      // C0: cross o-proj + residual + LN2
      {
        float rr=0.f;
        if(lane<kD)
          rr=h1+c_cbo+dot48d((const __half2*)covH, Wl+13440+lane*56);
        float s1=wsum(rr), s2=wsum(rr*rr);
        float mean=s1*(1.f/48.f);
        float rstd=rsqrtf(s2*(1.f/48.f)-mean*mean+1e-5f);
        h2=0;
        if(lane<kD){ h2=(rr-mean)*rstd*g2+bb2; h2H[lane]=__float2half(h2); }
      }
      wsync();
      // C1: FFN1 — 2 cols per lane (pipelined)
      {
        float a=c_fb1a+dot48d((const __half2*)h2H, Wl+16128+lane*56);
        float bcol=c_fb1b+dot48d((const __half2*)h2H, Wl+16128+(lane+64)*56);
        f1H[lane]=__float2half(fmaxf(a,0.f));
        f1H[lane+64]=__float2half(fmaxf(bcol,0.f));
      }
      wsync();
      // C2: FFN2 + residual + LN3 + output token
      {
        float rr=0.f;
        if(lane<kD)
          rr=h2+c_fb2+dot128d((const __half2*)f1H, Wl+23296+lane*136);
        float s1=wsum(rr), s2=wsum(rr*rr);
        float mean=s1*(1.f/48.f);
        float rstd=rsqrtf(s2*(1.f/48.f)-mean*mean+1e-5f);
        float cv=0.f;
        if(lane<kD){ cv=(rr-mean)*rstd*g3+bb3; cur=cv; }
        float y=wsum(cv*c_ow);
        if(lane==0) out[b*kT+t]=y+c_ob;
      }
    }
  }
}

extern "C" void kernel_launch(void* const* d_in, const int* in_sizes, int n_in,
                              void* d_out, int out_size, void* d_ws, size_t ws_size,
                              hipStream_t stream){
  // ws: Wh fp16 (reserve 65536 B), A fp32 NB, H1/H2/H3 fp16 NB each (~31.5 MiB).
  float* ws = (float*)d_ws;
  __half* Wh = (__half*)ws;
  const size_t NB = (size_t)kB*kS*kD;     // 3,145,728
  float*  A  = ws + 16384;
  __half* H1 = (__half*)(A + NB);
  __half* H2 = H1 + NB;
  __half* H3 = H2 + NB;

  k_embed<<<(kB*kS*kD+255)/256,256,0,stream>>>((const float*)d_in[0],(const float*)d_in[1],(const float*)d_in[2],A);
  k_qkv  <<<(kB*kS)/32,256,0,stream>>>(A,(const float*)d_in[4],(const float*)d_in[5],(const float*)d_in[6],
                                       (const float*)d_in[7],(const float*)d_in[8],(const float*)d_in[9],H1,H2,H3);
  k_attn <<<kB*kNH,256,0,stream>>>(H1,H2,H3,H1);
  k_oproj_ln<<<(kB*kS)/32,256,0,stream>>>(A,H1,(const float*)d_in[10],(const float*)d_in[11],
                                          (const float*)d_in[12],(const float*)d_in[13],H2);
  k_ffn_ln  <<<(kB*kS)/16,256,0,stream>>>(H2,(const float*)d_in[14],(const float*)d_in[15],(const float*)d_in[16],
                                          (const float*)d_in[17],(const float*)d_in[18],(const float*)d_in[19],A);
  k_ckv     <<<(kB*kS)/32,256,0,stream>>>(A,(const float*)d_in[32],(const float*)d_in[33],
                                          (const float*)d_in[34],(const float*)d_in[35],H1,H3);
  k_prep    <<<(26112+255)/256,256,0,stream>>>((const float*)d_in[20],(const float*)d_in[22],(const float*)d_in[24],
                                               (const float*)d_in[26],(const float*)d_in[30],(const float*)d_in[36],
                                               (const float*)d_in[40],(const float*)d_in[42],Wh);
  DecP P;
  P.dec_start=(const float*)d_in[3];
  P.sbq=(const float*)d_in[21]; P.sbk=(const float*)d_in[23]; P.sbv=(const float*)d_in[25]; P.sbo=(const float*)d_in[27];
  P.ln1g=(const float*)d_in[28]; P.ln1b=(const float*)d_in[29];
  P.cbq=(const float*)d_in[31]; P.cbo=(const float*)d_in[37];
  P.ln2g=(const float*)d_in[38]; P.ln2b=(const float*)d_in[39];
  P.fb1=(const float*)d_in[41]; P.fb2=(const float*)d_in[43];
  P.ln3g=(const float*)d_in[44]; P.ln3b=(const float*)d_in[45];
  P.ow=(const float*)d_in[46]; P.ob=(const float*)d_in[47];
  k_dec<<<kB,256,0,stream>>>(H1,H3,Wh,P,(float*)d_out);
}